// Round 4
// baseline (1497.533 us; speedup 1.0000x reference)
//
#include <hip/hip_runtime.h>
#include <hip/hip_bf16.h>

// ---------------------------------------------------------------------------
// Transformer encoder, B=8 T=1024 D_IN=320 L=6 H=8 DK=DV=64 DM=512 DI=2048.
// bf16 MFMA GEMMs (m97-style 2-phase structure), fused flash attention with
// swapped QK^T, f32 residual stream for accuracy.
// R3: TLP-first attn (2-wave blocks, no barrier, KVBLK=32) -> 92us, occupancy
//   34% — grid-limited (4096 waves on an 8192-wave chip).
// R4: flash-decoding split-K x2 (8192 waves, 100% nominal) + XCD-aware
//   swizzle so same-bh blocks share one L2 (2MB K/V per XCD) + combine pass.
// ---------------------------------------------------------------------------

typedef unsigned short bh16;                                  // bf16 bits
typedef __bf16 bf16x8 __attribute__((ext_vector_type(8)));
typedef float f32x4 __attribute__((ext_vector_type(4)));
typedef unsigned int u32x4 __attribute__((ext_vector_type(4)));
typedef unsigned int u32x2 __attribute__((ext_vector_type(2)));

#define DEVI static __device__ __forceinline__

DEVI bh16 f2bf(float f) {
  union { float f; unsigned u; } x; x.f = f;
  unsigned r = x.u + 0x7fffu + ((x.u >> 16) & 1u);
  return (bh16)(r >> 16);
}
DEVI float bf2f(bh16 u) {
  union { unsigned u; float f; } x; x.u = ((unsigned)u) << 16; return x.f;
}
DEVI bf16x8 ld16(const bh16* p) {
  return __builtin_bit_cast(bf16x8, *(const u32x4*)p);
}
DEVI f32x4 mfma16(bf16x8 a, bf16x8 b, f32x4 c) {
  return __builtin_amdgcn_mfma_f32_16x16x32_bf16(a, b, c, 0, 0, 0);
}
DEVI void async16(const void* g, void* l) {
  __builtin_amdgcn_global_load_lds(
      (const __attribute__((address_space(1))) void*)g,
      (__attribute__((address_space(3))) void*)l, 16, 0, 0);
}

// ---------------------------------------------------------------------------
// Weight transpose + f32->bf16 convert: in [K][N] f32 -> out [N][K] bf16.
// grid: (N/32, K/32, Layers)
// ---------------------------------------------------------------------------
__global__ __launch_bounds__(256) void tcvt(
    const float* __restrict__ in, bh16* __restrict__ out,
    int K, int N, long long inLS, long long outLS, int rowOff) {
  int l = blockIdx.z;
  in += (size_t)l * inLS;
  out += (size_t)l * outLS + (size_t)rowOff * K;
  __shared__ float t[32][33];
  int n0 = blockIdx.x * 32, k0 = blockIdx.y * 32;
  int tx = threadIdx.x & 31, ty = threadIdx.x >> 5;  // 32 x 8
#pragma unroll
  for (int i = 0; i < 4; i++)
    t[ty + 8 * i][tx] = in[(size_t)(k0 + ty + 8 * i) * N + n0 + tx];
  __syncthreads();
#pragma unroll
  for (int i = 0; i < 4; i++)
    out[(size_t)(n0 + ty + 8 * i) * K + k0 + tx] = f2bf(t[tx][ty + 8 * i]);
}

// bias concat: bq|bk|bv -> [L][1536] f32
__global__ __launch_bounds__(256) void bcat(
    const float* __restrict__ bq, const float* __restrict__ bk,
    const float* __restrict__ bv, float* __restrict__ out) {
  int l = blockIdx.x;
  for (int j = threadIdx.x; j < 1536; j += 256) {
    float v = (j < 512) ? bq[l * 512 + j]
            : (j < 1024) ? bk[l * 512 + j - 512] : bv[l * 512 + j - 1024];
    out[l * 1536 + j] = v;
  }
}

// f32 -> bf16 convert (padded_input)
__global__ __launch_bounds__(256) void cvt_in(
    const float* __restrict__ in, bh16* __restrict__ out, int n4) {
  int i = blockIdx.x * 256 + threadIdx.x;
  if (i < n4) {
    float4 v = ((const float4*)in)[i];
    u32x2 pk;
    pk[0] = (unsigned)f2bf(v.x) | ((unsigned)f2bf(v.y) << 16);
    pk[1] = (unsigned)f2bf(v.z) | ((unsigned)f2bf(v.w) << 16);
    *(u32x2*)(out + (size_t)i * 4) = pk;
  }
}

// ---------------------------------------------------------------------------
// GEMM: C[M][N] = A[M][K](bf16) * Bt[N][K](bf16)^T + bias, m97-style.
// 256 threads (4 waves, 2x2), BK=64, global_load_lds staging, 16x16x32 MFMA.
// ---------------------------------------------------------------------------
template <int BM, int BN, int RELU, int OUTF32>
__global__ __launch_bounds__(256, 2) void gemm_bt(
    const bh16* __restrict__ A, const bh16* __restrict__ Bt,
    const float* __restrict__ bias, void* __restrict__ Cout,
    int M, int N, int K) {
  constexpr int BK = 64;
  __shared__ __align__(16) bh16 As[BM * BK];
  __shared__ __align__(16) bh16 Bs[BN * BK];
  const int tid = threadIdx.x;
  const int wave = tid >> 6, lane = tid & 63;
  const int lq = lane & 15, grp = lane >> 4;
  const int m0 = blockIdx.y * BM, n0 = blockIdx.x * BN;
  constexpr int FM = BM / 32, FN = BN / 32;
  const int wr = wave >> 1, wc = wave & 1;
  f32x4 acc[FM][FN] = {};

  const int nk = K / BK;
  for (int kt = 0; kt < nk; ++kt) {
#pragma unroll
    for (int i = 0; i < BM / 32; ++i) {
      int off = i * 4096 + wave * 1024 + lane * 16;
      int row = off >> 7, col = off & 127;
      const char* g = (const char*)A + ((size_t)(m0 + row) * K + kt * BK) * 2 + col;
      async16(g, (char*)As + off);
    }
#pragma unroll
    for (int i = 0; i < BN / 32; ++i) {
      int off = i * 4096 + wave * 1024 + lane * 16;
      int row = off >> 7, col = off & 127;
      const char* g = (const char*)Bt + ((size_t)(n0 + row) * K + kt * BK) * 2 + col;
      async16(g, (char*)Bs + off);
    }
    __syncthreads();
#pragma unroll
    for (int kk = 0; kk < 2; ++kk) {
      bf16x8 af[FM], bfr[FN];
#pragma unroll
      for (int i = 0; i < FM; ++i) {
        int row = wr * (BM / 2) + i * 16 + lq;
        af[i] = ld16(As + row * BK + kk * 32 + grp * 8);
      }
#pragma unroll
      for (int j = 0; j < FN; ++j) {
        int row = wc * (BN / 2) + j * 16 + lq;
        bfr[j] = ld16(Bs + row * BK + kk * 32 + grp * 8);
      }
#pragma unroll
      for (int i = 0; i < FM; ++i)
#pragma unroll
        for (int j = 0; j < FN; ++j)
          acc[i][j] = mfma16(af[i], bfr[j], acc[i][j]);
    }
    __syncthreads();
  }
  // epilogue: D layout col=lane&15, row=(lane>>4)*4+r  [m89-verified]
#pragma unroll
  for (int i = 0; i < FM; ++i) {
#pragma unroll
    for (int j = 0; j < FN; ++j) {
      int col = n0 + wc * (BN / 2) + j * 16 + lq;
      float bv = bias[col];
#pragma unroll
      for (int r = 0; r < 4; ++r) {
        int row = m0 + wr * (BM / 2) + i * 16 + grp * 4 + r;
        float v = acc[i][j][r] + bv;
        if (RELU) v = fmaxf(v, 0.f);
        if (OUTF32) ((float*)Cout)[(size_t)row * N + col] = v;
        else ((bh16*)Cout)[(size_t)row * N + col] = f2bf(v);
      }
    }
  }
}

// ---------------------------------------------------------------------------
// LayerNorm after input projection: xb/xf = LN(in)*g+b + pe[t]
// one wave per row (512 cols, 8/lane)
// ---------------------------------------------------------------------------
__global__ __launch_bounds__(256) void ln_pe_k(
    const float* __restrict__ in, const float* __restrict__ g,
    const float* __restrict__ bta, const float* __restrict__ pe,
    float* __restrict__ xf, bh16* __restrict__ xb) {
  int wave = threadIdx.x >> 6, lane = threadIdx.x & 63;
  int row = blockIdx.x * 4 + wave;
  int t = row & 1023;
  const float* xr = in + (size_t)row * 512 + lane * 8;
  float4 a0 = ((const float4*)xr)[0], a1 = ((const float4*)xr)[1];
  float v[8] = {a0.x, a0.y, a0.z, a0.w, a1.x, a1.y, a1.z, a1.w};
  float s = 0.f, ss = 0.f;
#pragma unroll
  for (int j = 0; j < 8; j++) { s += v[j]; ss += v[j] * v[j]; }
#pragma unroll
  for (int m = 1; m < 64; m <<= 1) { s += __shfl_xor(s, m); ss += __shfl_xor(ss, m); }
  float mu = s * (1.f / 512.f);
  float rstd = rsqrtf(ss * (1.f / 512.f) - mu * mu + 1e-5f);
  int c0 = lane * 8;
  float o[8];
  u32x4 pk;
#pragma unroll
  for (int j = 0; j < 8; j++) {
    int c = c0 + j;
    o[j] = (v[j] - mu) * rstd * g[c] + bta[c] + pe[(size_t)t * 512 + c];
  }
  float4* xo = (float4*)(xf + (size_t)row * 512 + c0);
  xo[0] = make_float4(o[0], o[1], o[2], o[3]);
  xo[1] = make_float4(o[4], o[5], o[6], o[7]);
#pragma unroll
  for (int j = 0; j < 4; j++)
    pk[j] = (unsigned)f2bf(o[2 * j]) | ((unsigned)f2bf(o[2 * j + 1]) << 16);
  *(u32x4*)(xb + (size_t)row * 512 + c0) = pk;
}

// ---------------------------------------------------------------------------
// LayerNorm with residual + pad-mask: out = LN(gout + res)*g+b * nonpad
// ---------------------------------------------------------------------------
__global__ __launch_bounds__(256) void ln_res_k(
    const float* __restrict__ gout, const float* __restrict__ res,
    const float* __restrict__ g, const float* __restrict__ bta,
    const int* __restrict__ lens,
    float* __restrict__ xf, bh16* __restrict__ xb) {
  int wave = threadIdx.x >> 6, lane = threadIdx.x & 63;
  int row = blockIdx.x * 4 + wave;
  int b = row >> 10, t = row & 1023;
  float nonpad = (t < lens[b]) ? 1.f : 0.f;
  const float* xr = gout + (size_t)row * 512 + lane * 8;
  const float* rr = res + (size_t)row * 512 + lane * 8;
  float4 a0 = ((const float4*)xr)[0], a1 = ((const float4*)xr)[1];
  float4 r0 = ((const float4*)rr)[0], r1 = ((const float4*)rr)[1];
  float v[8] = {a0.x + r0.x, a0.y + r0.y, a0.z + r0.z, a0.w + r0.w,
                a1.x + r1.x, a1.y + r1.y, a1.z + r1.z, a1.w + r1.w};
  float s = 0.f, ss = 0.f;
#pragma unroll
  for (int j = 0; j < 8; j++) { s += v[j]; ss += v[j] * v[j]; }
#pragma unroll
  for (int m = 1; m < 64; m <<= 1) { s += __shfl_xor(s, m); ss += __shfl_xor(ss, m); }
  float mu = s * (1.f / 512.f);
  float rstd = rsqrtf(ss * (1.f / 512.f) - mu * mu + 1e-5f);
  int c0 = lane * 8;
  float o[8];
  u32x4 pk;
#pragma unroll
  for (int j = 0; j < 8; j++) {
    int c = c0 + j;
    o[j] = ((v[j] - mu) * rstd * g[c] + bta[c]) * nonpad;
  }
  float4* xo = (float4*)(xf + (size_t)row * 512 + c0);
  xo[0] = make_float4(o[0], o[1], o[2], o[3]);
  xo[1] = make_float4(o[4], o[5], o[6], o[7]);
#pragma unroll
  for (int j = 0; j < 4; j++)
    pk[j] = (unsigned)f2bf(o[2 * j]) | ((unsigned)f2bf(o[2 * j + 1]) << 16);
  *(u32x4*)(xb + (size_t)row * 512 + c0) = pk;
}

// ---------------------------------------------------------------------------
// V transpose: qkv V-part [b*1024+t][1024 + h*64+d] -> vt[(bh*64+d)][t]
// grid (32, 2, 64)
// ---------------------------------------------------------------------------
__global__ __launch_bounds__(256) void vtrans(
    const bh16* __restrict__ qkv, bh16* __restrict__ vt) {
  int bh = blockIdx.z, b = bh >> 3, h = bh & 7;
  __shared__ bh16 t[32][33];
  int t0 = blockIdx.x * 32, d0 = blockIdx.y * 32;
  int tx = threadIdx.x & 31, ty = threadIdx.x >> 5;
  const bh16* src = qkv + (size_t)(b * 1024) * 1536 + 1024 + h * 64;
#pragma unroll
  for (int i = 0; i < 4; i++)
    t[ty + 8 * i][tx] = src[(size_t)(t0 + ty + 8 * i) * 1536 + d0 + tx];
  __syncthreads();
  bh16* dst = vt + ((size_t)bh * 64 + d0) * 1024 + t0;
#pragma unroll
  for (int i = 0; i < 4; i++)
    dst[(size_t)(ty + 8 * i) * 1024 + tx] = t[tx][ty + 8 * i];
}

// ---------------------------------------------------------------------------
// Fused flash attention, split-K flash-decoding. 1-D grid 4096 = {2 splits x
// 32 qtiles x 64 bh}, XCD-swizzled so all blocks sharing a bh land on ONE XCD
// (8 bh x 256KB K/V = 2MB fits 4MB L2). 128 thr = 2 independent waves x 16 q.
// No barriers, KVBLK=32, tail-only mask, defer-max. Writes unnormalized
// O-partials (f32) + per-q (m, lsum); acomb merges the two splits.
// ---------------------------------------------------------------------------
__global__ __launch_bounds__(128) void attn_k(
    const bh16* __restrict__ qkv, const bh16* __restrict__ vt,
    const int* __restrict__ lens, float* __restrict__ Opart,
    float* __restrict__ Oml) {
  constexpr int LDP = 40;  // 32 P entries + pad; 80B row stride (16B-aligned)
  __shared__ __align__(16) bh16 P[2][16 * LDP];
  // bijective XCD swizzle: p%8 = XCD (HW round-robin); bh = (slot>>6)*8+xcd
  int p = blockIdx.x;
  int xcd = p & 7, slot = p >> 3;
  int bh = ((slot >> 6) << 3) + xcd;
  int qts = slot & 63;
  int qt = qts >> 1, s = qts & 1;
  int b = bh >> 3, h = bh & 7;
  int wave = threadIdx.x >> 6, lane = threadIdx.x & 63;
  int lq = lane & 15, grp = lane >> 4;
  int len = lens[b];

  size_t qrow = (size_t)(b * 1024 + qt * 32 + wave * 16 + lq);
  const bh16* Qp = qkv + qrow * 1536 + h * 64;
  bf16x8 qf0 = ld16(Qp + grp * 8);
  bf16x8 qf1 = ld16(Qp + 32 + grp * 8);
  const bh16* Kbase = qkv + (size_t)(b * 1024) * 1536 + 512 + h * 64;
  const bh16* Vbase = vt + (size_t)(bh * 64) * 1024;
  bh16* Pw = P[wave];

  f32x4 oacc[4] = {};
  float m = -1e30f, lsum = 0.f;
  int nkbt = (len + 31) >> 5;       // total 32-key blocks (>=16 since len>=512)
  int nk0 = (nkbt + 1) >> 1;
  int kbLo = s ? nk0 : 0;
  int kbHi = s ? nkbt : nk0;        // both splits non-empty (nkbt >= 2)

  for (int kb = kbLo; kb < kbHi; ++kb) {
    int k32 = kb * 32;
    // K loads (used by QK below)
    bf16x8 kf[2][2];
#pragma unroll
    for (int sv = 0; sv < 2; ++sv) {
      const bh16* Kp = Kbase + (size_t)(k32 + sv * 16 + lq) * 1536;
      kf[sv][0] = ld16(Kp + grp * 8);
      kf[sv][1] = ld16(Kp + 32 + grp * 8);
    }
    // V loads issued now; stay in flight through QK + softmax
    bf16x8 vf[4];
#pragma unroll
    for (int dt = 0; dt < 4; ++dt)
      vf[dt] = ld16(Vbase + (size_t)(dt * 16 + lq) * 1024 + k32 + grp * 8);
    // QK^T
    f32x4 st[2];
    __builtin_amdgcn_s_setprio(1);
#pragma unroll
    for (int sv = 0; sv < 2; ++sv) {
      f32x4 z = {};
      z = mfma16(kf[sv][0], qf0, z);
      z = mfma16(kf[sv][1], qf1, z);
      st[sv] = z;
    }
    __builtin_amdgcn_s_setprio(0);
    // scale + (tail-only) mask + row-max
    float tmax = -1e30f;
    if (k32 + 32 > len) {
#pragma unroll
      for (int sv = 0; sv < 2; ++sv)
#pragma unroll
        for (int r = 0; r < 4; ++r) {
          int key = k32 + sv * 16 + grp * 4 + r;
          float v = st[sv][r] * 0.125f;
          v = (key < len) ? v : -1e30f;
          st[sv][r] = v;
          tmax = fmaxf(tmax, v);
        }
    } else {
#pragma unroll
      for (int sv = 0; sv < 2; ++sv)
#pragma unroll
        for (int r = 0; r < 4; ++r) {
          float v = st[sv][r] * 0.125f;
          st[sv][r] = v;
          tmax = fmaxf(tmax, v);
        }
    }
    tmax = fmaxf(tmax, __shfl_xor(tmax, 16));
    tmax = fmaxf(tmax, __shfl_xor(tmax, 32));
    // defer-max (T13, THR=8)
    float newm = fmaxf(m, tmax);
    if (!__all(newm - m <= 8.f)) {
      float sc = __expf(m - newm);
      m = newm;
      lsum *= sc;
#pragma unroll
      for (int r = 0; r < 4; ++r) {
        float scr = __shfl(sc, grp * 4 + r);
#pragma unroll
        for (int dt = 0; dt < 4; ++dt) oacc[dt][r] *= scr;
      }
    }
    // P = exp(S - m), row-sum, per-wave LDS store (row=q, 32 entries)
    float rs = 0.f;
#pragma unroll
    for (int sv = 0; sv < 2; ++sv) {
      float p0 = __expf(st[sv][0] - m), p1 = __expf(st[sv][1] - m);
      float p2 = __expf(st[sv][2] - m), p3 = __expf(st[sv][3] - m);
      rs += (p0 + p1) + (p2 + p3);
      u32x2 pk;
      pk[0] = (unsigned)f2bf(p0) | ((unsigned)f2bf(p1) << 16);
      pk[1] = (unsigned)f2bf(p2) | ((unsigned)f2bf(p3) << 16);
      *(u32x2*)&Pw[lq * LDP + sv * 16 + grp * 4] = pk;
    }
    rs += __shfl_xor(rs, 16);
    rs += __shfl_xor(rs, 32);
    lsum += rs;
    // PV (in-wave LDS ordering via compiler lgkmcnt; no barrier needed)
    bf16x8 pa = ld16(Pw + lq * LDP + grp * 8);
    __builtin_amdgcn_s_setprio(1);
#pragma unroll
    for (int dt = 0; dt < 4; ++dt)
      oacc[dt] = mfma16(pa, vf[dt], oacc[dt]);
    __builtin_amdgcn_s_setprio(0);
  }
  // store unnormalized partials + (m, lsum)
  size_t rbase = (size_t)s * 65536 + (size_t)bh * 1024 + qt * 32 + wave * 16;
  float* Ob = Opart + rbase * 64;
#pragma unroll
  for (int r = 0; r < 4; ++r)
#pragma unroll
    for (int dt = 0; dt < 4; ++dt)
      Ob[(size_t)(grp * 4 + r) * 64 + dt * 16 + lq] = oacc[dt][r];
  if (grp == 0) {
    Oml[(rbase + lq) * 2] = m;
    Oml[(rbase + lq) * 2 + 1] = lsum;
  }
}

// ---------------------------------------------------------------------------
// Split-K combine: o[b,t,h*64+d] = (w0*O0 + w1*O1) / (w0*l0 + w1*l1)
// grid 16384 x 256 (4 rows/block, lane = d)
// ---------------------------------------------------------------------------
__global__ __launch_bounds__(256) void acomb(
    const float* __restrict__ Opart, const float* __restrict__ Oml,
    bh16* __restrict__ o) {
  int w = threadIdx.x >> 6, lane = threadIdx.x & 63;
  int r = blockIdx.x * 4 + w;                   // 0..65535 = bh*1024 + t
  int bh = r >> 10, t = r & 1023, b = bh >> 3, h = bh & 7;
  float m0 = Oml[(size_t)r * 2], l0 = Oml[(size_t)r * 2 + 1];
  float m1 = Oml[(size_t)(65536 + r) * 2], l1 = Oml[(size_t)(65536 + r) * 2 + 1];
  float M = fmaxf(m0, m1);
  float w0 = __expf(m0 - M), w1 = __expf(m1 - M);
  float inv = 1.f / (w0 * l0 + w1 * l1);
  float v0 = Opart[(size_t)r * 64 + lane];
  float v1 = Opart[(size_t)(65536 + r) * 64 + lane];
  float v = (w0 * v0 + w1 * v1) * inv;
  o[(size_t)(b * 1024 + t) * 512 + h * 64 + lane] = f2bf(v);
}

// ---------------------------------------------------------------------------
// host
// ---------------------------------------------------------------------------
extern "C" void kernel_launch(void* const* d_in, const int* in_sizes, int n_in,
                              void* d_out, int out_size, void* d_ws, size_t ws_size,
                              hipStream_t stream) {
  const float* padded = (const float*)d_in[0];
  const int* lens = (const int*)d_in[1];
  const float* w_in = (const float*)d_in[2];
  const float* b_in = (const float*)d_in[3];
  const float* ln_in_g = (const float*)d_in[4];
  const float* ln_in_b = (const float*)d_in[5];
  const float* pe = (const float*)d_in[6];
  const float* wq = (const float*)d_in[7];
  const float* bq = (const float*)d_in[8];
  const float* wk = (const float*)d_in[9];
  const float* bk = (const float*)d_in[10];
  const float* wv = (const float*)d_in[11];
  const float* bv = (const float*)d_in[12];
  const float* wfc = (const float*)d_in[13];
  const float* bfc = (const float*)d_in[14];
  const float* ln1_g = (const float*)d_in[15];
  const float* ln1_b = (const float*)d_in[16];
  const float* w1 = (const float*)d_in[17];
  const float* b1 = (const float*)d_in[18];
  const float* w2 = (const float*)d_in[19];
  const float* b2 = (const float*)d_in[20];
  const float* ln2_g = (const float*)d_in[21];
  const float* ln2_b = (const float*)d_in[22];

  char* ws = (char*)d_ws;
  size_t off = 0;
  auto alloc = [&](size_t bytes) -> char* {
    char* p = ws + off;
    off += (bytes + 255) & ~(size_t)255;
    return p;
  };
  bh16* WinT  = (bh16*)alloc((size_t)512 * 320 * 2);
  bh16* WqkvT = (bh16*)alloc((size_t)6 * 1536 * 512 * 2);
  bh16* WfcT  = (bh16*)alloc((size_t)6 * 512 * 512 * 2);
  bh16* W1T   = (bh16*)alloc((size_t)6 * 2048 * 512 * 2);
  bh16* W2T   = (bh16*)alloc((size_t)6 * 512 * 2048 * 2);
  float* bqkv = (float*)alloc((size_t)6 * 1536 * 4);
  bh16* xb    = (bh16*)alloc((size_t)8192 * 512 * 2);
  float* xf   = (float*)alloc((size_t)8192 * 512 * 4);
  bh16* qkvb  = (bh16*)alloc((size_t)8192 * 1536 * 2);
  bh16* vt    = (bh16*)alloc((size_t)64 * 64 * 1024 * 2);
  bh16* ob    = (bh16*)alloc((size_t)8192 * 512 * 2);
  float* tmp32 = (float*)alloc((size_t)8192 * 512 * 4);
  bh16* hbuf  = (bh16*)alloc((size_t)8192 * 2048 * 2);
  float* Opart = (float*)alloc((size_t)2 * 65536 * 64 * 4);
  float* Oml   = (float*)alloc((size_t)2 * 65536 * 2 * 4);
  bh16* padb  = hbuf;  // alias: hbuf is free until w1 GEMM
  if (off > ws_size) return;  // loud failure (output stays poisoned)

  // weights -> bf16 transposed
  tcvt<<<dim3(16, 10, 1), 256, 0, stream>>>(w_in, WinT, 320, 512, 0, 0, 0);
  tcvt<<<dim3(16, 16, 6), 256, 0, stream>>>(wq, WqkvT, 512, 512, 512 * 512, 1536 * 512, 0);
  tcvt<<<dim3(16, 16, 6), 256, 0, stream>>>(wk, WqkvT, 512, 512, 512 * 512, 1536 * 512, 512);
  tcvt<<<dim3(16, 16, 6), 256, 0, stream>>>(wv, WqkvT, 512, 512, 512 * 512, 1536 * 512, 1024);
  tcvt<<<dim3(16, 16, 6), 256, 0, stream>>>(wfc, WfcT, 512, 512, 512 * 512, 512 * 512, 0);
  tcvt<<<dim3(64, 16, 6), 256, 0, stream>>>(w1, W1T, 512, 2048, (long long)512 * 2048, (long long)2048 * 512, 0);
  tcvt<<<dim3(16, 64, 6), 256, 0, stream>>>(w2, W2T, 2048, 512, (long long)2048 * 512, (long long)512 * 2048, 0);
  bcat<<<6, 256, 0, stream>>>(bq, bk, bv, bqkv);
  cvt_in<<<2560, 256, 0, stream>>>(padded, padb, 655360);

  // input projection + LN + PE
  gemm_bt<128, 64, 0, 1><<<dim3(8, 64), 256, 0, stream>>>(
      padb, WinT, b_in, tmp32, 8192, 512, 320);
  ln_pe_k<<<2048, 256, 0, stream>>>(tmp32, ln_in_g, ln_in_b, pe, xf, xb);

  for (int l = 0; l < 6; ++l) {
    gemm_bt<128, 128, 0, 0><<<dim3(12, 64), 256, 0, stream>>>(
        xb, WqkvT + (size_t)l * 1536 * 512, bqkv + l * 1536, qkvb, 8192, 1536, 512);
    vtrans<<<dim3(32, 2, 64), 256, 0, stream>>>(qkvb, vt);
    attn_k<<<4096, 128, 0, stream>>>(qkvb, vt, lens, Opart, Oml);
    acomb<<<16384, 256, 0, stream>>>(Opart, Oml, ob);
    gemm_bt<128, 64, 0, 1><<<dim3(8, 64), 256, 0, stream>>>(
        ob, WfcT + (size_t)l * 512 * 512, bfc + l * 512, tmp32, 8192, 512, 512);
    ln_res_k<<<2048, 256, 0, stream>>>(tmp32, xf, ln1_g + l * 512, ln1_b + l * 512,
                                       lens, xf, xb);
    gemm_bt<128, 128, 1, 0><<<dim3(16, 64), 256, 0, stream>>>(
        xb, W1T + (size_t)l * 2048 * 512, b1 + l * 2048, hbuf, 8192, 2048, 512);
    gemm_bt<128, 64, 0, 1><<<dim3(8, 64), 256, 0, stream>>>(
        hbuf, W2T + (size_t)l * 512 * 2048, b2 + l * 512, tmp32, 8192, 512, 2048);
    float* xfo = (l == 5) ? (float*)d_out : xf;
    ln_res_k<<<2048, 256, 0, stream>>>(tmp32, xf, ln2_g + l * 512, ln2_b + l * 512,
                                       lens, xfo, xb);
  }
}

// Round 5
// 1091.039 us; speedup vs baseline: 1.3726x; 1.3726x over previous
//
#include <hip/hip_runtime.h>
#include <hip/hip_bf16.h>

// ---------------------------------------------------------------------------
// Transformer encoder, B=8 T=1024 D_IN=320 L=6 H=8 DK=DV=64 DM=512 DI=2048.
// bf16 MFMA GEMMs (m97-style 2-phase structure), fused flash attention with
// swapped QK^T, f32 residual stream for accuracy.
// R4 post-mortem: split-K added 33MB partial traffic, occupancy stuck at 37%
//   (latency-serialized, not grid-limited) -> reverted.
// R5: attn restructured to staged 2-phase (T3-min): 4 waves share K/V tiles
//   staged via global_load_lds (dbuf, 1 barrier/iter), T2 XOR swizzle
//   (inverse-swz source + swz read, linear dest), KVBLK=64, q-tile skip.
// ---------------------------------------------------------------------------

typedef unsigned short bh16;                                  // bf16 bits
typedef __bf16 bf16x8 __attribute__((ext_vector_type(8)));
typedef float f32x4 __attribute__((ext_vector_type(4)));
typedef unsigned int u32x4 __attribute__((ext_vector_type(4)));
typedef unsigned int u32x2 __attribute__((ext_vector_type(2)));

#define DEVI static __device__ __forceinline__

DEVI bh16 f2bf(float f) {
  union { float f; unsigned u; } x; x.f = f;
  unsigned r = x.u + 0x7fffu + ((x.u >> 16) & 1u);
  return (bh16)(r >> 16);
}
DEVI float bf2f(bh16 u) {
  union { unsigned u; float f; } x; x.u = ((unsigned)u) << 16; return x.f;
}
DEVI bf16x8 ld16(const bh16* p) {
  return __builtin_bit_cast(bf16x8, *(const u32x4*)p);
}
DEVI bf16x8 ld16b(const char* p) {
  return __builtin_bit_cast(bf16x8, *(const u32x4*)p);
}
DEVI f32x4 mfma16(bf16x8 a, bf16x8 b, f32x4 c) {
  return __builtin_amdgcn_mfma_f32_16x16x32_bf16(a, b, c, 0, 0, 0);
}
DEVI void async16(const void* g, void* l) {
  __builtin_amdgcn_global_load_lds(
      (const __attribute__((address_space(1))) void*)g,
      (__attribute__((address_space(3))) void*)l, 16, 0, 0);
}

// ---------------------------------------------------------------------------
// Weight transpose + f32->bf16 convert: in [K][N] f32 -> out [N][K] bf16.
// grid: (N/32, K/32, Layers)
// ---------------------------------------------------------------------------
__global__ __launch_bounds__(256) void tcvt(
    const float* __restrict__ in, bh16* __restrict__ out,
    int K, int N, long long inLS, long long outLS, int rowOff) {
  int l = blockIdx.z;
  in += (size_t)l * inLS;
  out += (size_t)l * outLS + (size_t)rowOff * K;
  __shared__ float t[32][33];
  int n0 = blockIdx.x * 32, k0 = blockIdx.y * 32;
  int tx = threadIdx.x & 31, ty = threadIdx.x >> 5;  // 32 x 8
#pragma unroll
  for (int i = 0; i < 4; i++)
    t[ty + 8 * i][tx] = in[(size_t)(k0 + ty + 8 * i) * N + n0 + tx];
  __syncthreads();
#pragma unroll
  for (int i = 0; i < 4; i++)
    out[(size_t)(n0 + ty + 8 * i) * K + k0 + tx] = f2bf(t[tx][ty + 8 * i]);
}

// bias concat: bq|bk|bv -> [L][1536] f32
__global__ __launch_bounds__(256) void bcat(
    const float* __restrict__ bq, const float* __restrict__ bk,
    const float* __restrict__ bv, float* __restrict__ out) {
  int l = blockIdx.x;
  for (int j = threadIdx.x; j < 1536; j += 256) {
    float v = (j < 512) ? bq[l * 512 + j]
            : (j < 1024) ? bk[l * 512 + j - 512] : bv[l * 512 + j - 1024];
    out[l * 1536 + j] = v;
  }
}

// f32 -> bf16 convert (padded_input)
__global__ __launch_bounds__(256) void cvt_in(
    const float* __restrict__ in, bh16* __restrict__ out, int n4) {
  int i = blockIdx.x * 256 + threadIdx.x;
  if (i < n4) {
    float4 v = ((const float4*)in)[i];
    u32x2 pk;
    pk[0] = (unsigned)f2bf(v.x) | ((unsigned)f2bf(v.y) << 16);
    pk[1] = (unsigned)f2bf(v.z) | ((unsigned)f2bf(v.w) << 16);
    *(u32x2*)(out + (size_t)i * 4) = pk;
  }
}

// ---------------------------------------------------------------------------
// GEMM: C[M][N] = A[M][K](bf16) * Bt[N][K](bf16)^T + bias, m97-style.
// 256 threads (4 waves, 2x2), BK=64, global_load_lds staging, 16x16x32 MFMA.
// ---------------------------------------------------------------------------
template <int BM, int BN, int RELU, int OUTF32>
__global__ __launch_bounds__(256, 2) void gemm_bt(
    const bh16* __restrict__ A, const bh16* __restrict__ Bt,
    const float* __restrict__ bias, void* __restrict__ Cout,
    int M, int N, int K) {
  constexpr int BK = 64;
  __shared__ __align__(16) bh16 As[BM * BK];
  __shared__ __align__(16) bh16 Bs[BN * BK];
  const int tid = threadIdx.x;
  const int wave = tid >> 6, lane = tid & 63;
  const int lq = lane & 15, grp = lane >> 4;
  const int m0 = blockIdx.y * BM, n0 = blockIdx.x * BN;
  constexpr int FM = BM / 32, FN = BN / 32;
  const int wr = wave >> 1, wc = wave & 1;
  f32x4 acc[FM][FN] = {};

  const int nk = K / BK;
  for (int kt = 0; kt < nk; ++kt) {
#pragma unroll
    for (int i = 0; i < BM / 32; ++i) {
      int off = i * 4096 + wave * 1024 + lane * 16;
      int row = off >> 7, col = off & 127;
      const char* g = (const char*)A + ((size_t)(m0 + row) * K + kt * BK) * 2 + col;
      async16(g, (char*)As + off);
    }
#pragma unroll
    for (int i = 0; i < BN / 32; ++i) {
      int off = i * 4096 + wave * 1024 + lane * 16;
      int row = off >> 7, col = off & 127;
      const char* g = (const char*)Bt + ((size_t)(n0 + row) * K + kt * BK) * 2 + col;
      async16(g, (char*)Bs + off);
    }
    __syncthreads();
#pragma unroll
    for (int kk = 0; kk < 2; ++kk) {
      bf16x8 af[FM], bfr[FN];
#pragma unroll
      for (int i = 0; i < FM; ++i) {
        int row = wr * (BM / 2) + i * 16 + lq;
        af[i] = ld16(As + row * BK + kk * 32 + grp * 8);
      }
#pragma unroll
      for (int j = 0; j < FN; ++j) {
        int row = wc * (BN / 2) + j * 16 + lq;
        bfr[j] = ld16(Bs + row * BK + kk * 32 + grp * 8);
      }
#pragma unroll
      for (int i = 0; i < FM; ++i)
#pragma unroll
        for (int j = 0; j < FN; ++j)
          acc[i][j] = mfma16(af[i], bfr[j], acc[i][j]);
    }
    __syncthreads();
  }
  // epilogue: D layout col=lane&15, row=(lane>>4)*4+r  [m89-verified]
#pragma unroll
  for (int i = 0; i < FM; ++i) {
#pragma unroll
    for (int j = 0; j < FN; ++j) {
      int col = n0 + wc * (BN / 2) + j * 16 + lq;
      float bv = bias[col];
#pragma unroll
      for (int r = 0; r < 4; ++r) {
        int row = m0 + wr * (BM / 2) + i * 16 + grp * 4 + r;
        float v = acc[i][j][r] + bv;
        if (RELU) v = fmaxf(v, 0.f);
        if (OUTF32) ((float*)Cout)[(size_t)row * N + col] = v;
        else ((bh16*)Cout)[(size_t)row * N + col] = f2bf(v);
      }
    }
  }
}

// ---------------------------------------------------------------------------
// LayerNorm after input projection: xb/xf = LN(in)*g+b + pe[t]
// one wave per row (512 cols, 8/lane)
// ---------------------------------------------------------------------------
__global__ __launch_bounds__(256) void ln_pe_k(
    const float* __restrict__ in, const float* __restrict__ g,
    const float* __restrict__ bta, const float* __restrict__ pe,
    float* __restrict__ xf, bh16* __restrict__ xb) {
  int wave = threadIdx.x >> 6, lane = threadIdx.x & 63;
  int row = blockIdx.x * 4 + wave;
  int t = row & 1023;
  const float* xr = in + (size_t)row * 512 + lane * 8;
  float4 a0 = ((const float4*)xr)[0], a1 = ((const float4*)xr)[1];
  float v[8] = {a0.x, a0.y, a0.z, a0.w, a1.x, a1.y, a1.z, a1.w};
  float s = 0.f, ss = 0.f;
#pragma unroll
  for (int j = 0; j < 8; j++) { s += v[j]; ss += v[j] * v[j]; }
#pragma unroll
  for (int m = 1; m < 64; m <<= 1) { s += __shfl_xor(s, m); ss += __shfl_xor(ss, m); }
  float mu = s * (1.f / 512.f);
  float rstd = rsqrtf(ss * (1.f / 512.f) - mu * mu + 1e-5f);
  int c0 = lane * 8;
  float o[8];
  u32x4 pk;
#pragma unroll
  for (int j = 0; j < 8; j++) {
    int c = c0 + j;
    o[j] = (v[j] - mu) * rstd * g[c] + bta[c] + pe[(size_t)t * 512 + c];
  }
  float4* xo = (float4*)(xf + (size_t)row * 512 + c0);
  xo[0] = make_float4(o[0], o[1], o[2], o[3]);
  xo[1] = make_float4(o[4], o[5], o[6], o[7]);
#pragma unroll
  for (int j = 0; j < 4; j++)
    pk[j] = (unsigned)f2bf(o[2 * j]) | ((unsigned)f2bf(o[2 * j + 1]) << 16);
  *(u32x4*)(xb + (size_t)row * 512 + c0) = pk;
}

// ---------------------------------------------------------------------------
// LayerNorm with residual + pad-mask: out = LN(gout + res)*g+b * nonpad
// ---------------------------------------------------------------------------
__global__ __launch_bounds__(256) void ln_res_k(
    const float* __restrict__ gout, const float* __restrict__ res,
    const float* __restrict__ g, const float* __restrict__ bta,
    const int* __restrict__ lens,
    float* __restrict__ xf, bh16* __restrict__ xb) {
  int wave = threadIdx.x >> 6, lane = threadIdx.x & 63;
  int row = blockIdx.x * 4 + wave;
  int b = row >> 10, t = row & 1023;
  float nonpad = (t < lens[b]) ? 1.f : 0.f;
  const float* xr = gout + (size_t)row * 512 + lane * 8;
  const float* rr = res + (size_t)row * 512 + lane * 8;
  float4 a0 = ((const float4*)xr)[0], a1 = ((const float4*)xr)[1];
  float4 r0 = ((const float4*)rr)[0], r1 = ((const float4*)rr)[1];
  float v[8] = {a0.x + r0.x, a0.y + r0.y, a0.z + r0.z, a0.w + r0.w,
                a1.x + r1.x, a1.y + r1.y, a1.z + r1.z, a1.w + r1.w};
  float s = 0.f, ss = 0.f;
#pragma unroll
  for (int j = 0; j < 8; j++) { s += v[j]; ss += v[j] * v[j]; }
#pragma unroll
  for (int m = 1; m < 64; m <<= 1) { s += __shfl_xor(s, m); ss += __shfl_xor(ss, m); }
  float mu = s * (1.f / 512.f);
  float rstd = rsqrtf(ss * (1.f / 512.f) - mu * mu + 1e-5f);
  int c0 = lane * 8;
  float o[8];
  u32x4 pk;
#pragma unroll
  for (int j = 0; j < 8; j++) {
    int c = c0 + j;
    o[j] = ((v[j] - mu) * rstd * g[c] + bta[c]) * nonpad;
  }
  float4* xo = (float4*)(xf + (size_t)row * 512 + c0);
  xo[0] = make_float4(o[0], o[1], o[2], o[3]);
  xo[1] = make_float4(o[4], o[5], o[6], o[7]);
#pragma unroll
  for (int j = 0; j < 4; j++)
    pk[j] = (unsigned)f2bf(o[2 * j]) | ((unsigned)f2bf(o[2 * j + 1]) << 16);
  *(u32x4*)(xb + (size_t)row * 512 + c0) = pk;
}

// ---------------------------------------------------------------------------
// V transpose: qkv V-part [b*1024+t][1024 + h*64+d] -> vt[(bh*64+d)][t]
// grid (32, 2, 64)
// ---------------------------------------------------------------------------
__global__ __launch_bounds__(256) void vtrans(
    const bh16* __restrict__ qkv, bh16* __restrict__ vt) {
  int bh = blockIdx.z, b = bh >> 3, h = bh & 7;
  __shared__ bh16 t[32][33];
  int t0 = blockIdx.x * 32, d0 = blockIdx.y * 32;
  int tx = threadIdx.x & 31, ty = threadIdx.x >> 5;
  const bh16* src = qkv + (size_t)(b * 1024) * 1536 + 1024 + h * 64;
#pragma unroll
  for (int i = 0; i < 4; i++)
    t[ty + 8 * i][tx] = src[(size_t)(t0 + ty + 8 * i) * 1536 + d0 + tx];
  __syncthreads();
  bh16* dst = vt + ((size_t)bh * 64 + d0) * 1024 + t0;
#pragma unroll
  for (int i = 0; i < 4; i++)
    dst[(size_t)(ty + 8 * i) * 1024 + tx] = t[tx][ty + 8 * i];
}

// ---------------------------------------------------------------------------
// Fused flash attention, staged 2-phase. grid 1024 = {16 qt x 64 bh},
// XCD-swizzled (same bh -> same XCD; 8 bh x 256KB K/V = 2MB per L2).
// Block = 4 waves x 16 q = 64 q-rows sharing K/V tiles. Per 64-key iter:
//   sync -> stage(next K[64][64]+Vt[64][64] via global_load_lds, T2-swizzled
//   source, linear LDS dest) -> compute(cur from LDS, swizzled reads).
// One barrier/iter; staging hides under compute (T3 minimum). Swapped QK^T,
// tail-only mask, defer-max, per-wave P in LDS. Q-tiles past len skipped.
// ---------------------------------------------------------------------------
__global__ __launch_bounds__(256) void attn_k(
    const bh16* __restrict__ qkv, const bh16* __restrict__ vt,
    const int* __restrict__ lens, bh16* __restrict__ o) {
  constexpr int LDP = 72;  // 64 P entries + pad (144B row stride, 16B aligned)
  __shared__ __align__(16) char Ks[2][8192];   // [key 0..63][d 0..63] swz
  __shared__ __align__(16) char Vs[2][8192];   // [d 0..63][t 0..63] swz
  __shared__ __align__(16) bh16 P[4][16 * LDP];
  // XCD swizzle: blockIdx -> XCD is round-robin (p&7). bh&7 == xcd so all
  // 16 q-tiles of one bh land on one XCD.
  int p = blockIdx.x;
  int xcd = p & 7, s = p >> 3;          // s in 0..127
  int bh = ((s & 7) << 3) | xcd;
  int qt = s >> 3;                      // 0..15
  int b = bh >> 3, h = bh & 7;
  int len = lens[b];
  if (qt * 64 >= len) return;           // uniform branch; padded q-tile
  int tid = threadIdx.x;
  int wave = tid >> 6, lane = tid & 63;
  int lq = lane & 15, grp = lane >> 4;

  size_t qrow = (size_t)(b * 1024 + qt * 64 + wave * 16 + lq);
  const bh16* Qp = qkv + qrow * 1536 + h * 64;
  bf16x8 qf0 = ld16(Qp + grp * 8);
  bf16x8 qf1 = ld16(Qp + 32 + grp * 8);
  const char* Kbase = (const char*)(qkv + (size_t)(b * 1024) * 1536 + 512 + h * 64);
  const char* Vbase = (const char*)(vt + (size_t)(bh * 64) * 1024);
  bh16* Pw = P[wave];

  f32x4 oacc[4] = {};
  float m = -1e30f, lsum = 0.f;
  int nkb = (len + 63) >> 6;

  // stage: LDS linear (wave-uniform base + lane*16), source inverse-swizzled
  auto stage = [&](int buf, int kb) {
#pragma unroll
    for (int t = 0; t < 2; ++t) {
      int off = (tid + t * 256) * 16;          // 0..8176
      int row = off >> 7, cb = off & 127;
      int sw = (row & 7) << 4;
      async16(Kbase + (size_t)(kb * 64 + row) * 3072 + (cb ^ sw), Ks[buf] + off);
    }
#pragma unroll
    for (int t = 0; t < 2; ++t) {
      int off = (tid + t * 256) * 16;
      int row = off >> 7, cb = off & 127;
      int sw = (row & 7) << 4;
      async16(Vbase + (size_t)row * 2048 + kb * 128 + (cb ^ sw), Vs[buf] + off);
    }
  };

  stage(0, 0);
  for (int kb = 0; kb < nkb; ++kb) {
    int cur = kb & 1;
    __syncthreads();                  // stage(kb) complete; prev readers done
    if (kb + 1 < nkb) stage(cur ^ 1, kb + 1);
    int k64 = kb * 64;
    // QK^T from LDS (swizzled reads)
    f32x4 st[4];
    __builtin_amdgcn_s_setprio(1);
#pragma unroll
    for (int sv = 0; sv < 4; ++sv) {
      int row = sv * 16 + lq, sw = (row & 7) << 4;
      const char* kp = Ks[cur] + row * 128;
      f32x4 z = {};
      z = mfma16(ld16b(kp + ((grp * 16) ^ sw)), qf0, z);
      z = mfma16(ld16b(kp + ((64 + grp * 16) ^ sw)), qf1, z);
      st[sv] = z;
    }
    __builtin_amdgcn_s_setprio(0);
    // scale + (tail-only) mask + row-max
    float tmax = -1e30f;
    if (k64 + 64 > len) {
#pragma unroll
      for (int sv = 0; sv < 4; ++sv)
#pragma unroll
        for (int r = 0; r < 4; ++r) {
          int key = k64 + sv * 16 + grp * 4 + r;
          float v = st[sv][r] * 0.125f;
          v = (key < len) ? v : -1e30f;
          st[sv][r] = v;
          tmax = fmaxf(tmax, v);
        }
    } else {
#pragma unroll
      for (int sv = 0; sv < 4; ++sv)
#pragma unroll
        for (int r = 0; r < 4; ++r) {
          float v = st[sv][r] * 0.125f;
          st[sv][r] = v;
          tmax = fmaxf(tmax, v);
        }
    }
    tmax = fmaxf(tmax, __shfl_xor(tmax, 16));
    tmax = fmaxf(tmax, __shfl_xor(tmax, 32));
    // defer-max (T13, THR=8)
    float newm = fmaxf(m, tmax);
    if (!__all(newm - m <= 8.f)) {
      float sc = __expf(m - newm);
      m = newm;
      lsum *= sc;
#pragma unroll
      for (int r = 0; r < 4; ++r) {
        float scr = __shfl(sc, grp * 4 + r);
#pragma unroll
        for (int dt = 0; dt < 4; ++dt) oacc[dt][r] *= scr;
      }
    }
    // P = exp(S - m), row-sum, per-wave LDS (row=q, 64 entries)
    float rs = 0.f;
#pragma unroll
    for (int sv = 0; sv < 4; ++sv) {
      float p0 = __expf(st[sv][0] - m), p1 = __expf(st[sv][1] - m);
      float p2 = __expf(st[sv][2] - m), p3 = __expf(st[sv][3] - m);
      rs += (p0 + p1) + (p2 + p3);
      u32x2 pk;
      pk[0] = (unsigned)f2bf(p0) | ((unsigned)f2bf(p1) << 16);
      pk[1] = (unsigned)f2bf(p2) | ((unsigned)f2bf(p3) << 16);
      *(u32x2*)&Pw[lq * LDP + sv * 16 + grp * 4] = pk;
    }
    rs += __shfl_xor(rs, 16);
    rs += __shfl_xor(rs, 32);
    lsum += rs;
    // PV from LDS (in-wave lgkmcnt ordering for P; swizzled V reads)
#pragma unroll
    for (int kk = 0; kk < 2; ++kk) {
      bf16x8 pa = ld16(Pw + lq * LDP + kk * 32 + grp * 8);
      __builtin_amdgcn_s_setprio(1);
#pragma unroll
      for (int dt = 0; dt < 4; ++dt) {
        int row = dt * 16 + lq, sw = (row & 7) << 4;
        bf16x8 vfr = ld16b(Vs[cur] + row * 128 + ((kk * 64 + grp * 16) ^ sw));
        oacc[dt] = mfma16(pa, vfr, oacc[dt]);
      }
      __builtin_amdgcn_s_setprio(0);
    }
  }
  // normalize + store (softmax state at lane q=lq; O rows q=grp*4+r)
#pragma unroll
  for (int r = 0; r < 4; ++r) {
    float li = __shfl(lsum, grp * 4 + r);
    float inv = 1.f / li;
    int row = qt * 64 + wave * 16 + grp * 4 + r;
    bh16* orow = o + (size_t)(b * 1024 + row) * 512 + h * 64;
#pragma unroll
    for (int dt = 0; dt < 4; ++dt) orow[dt * 16 + lq] = f2bf(oacc[dt][r] * inv);
  }
}

// ---------------------------------------------------------------------------
// host
// ---------------------------------------------------------------------------
extern "C" void kernel_launch(void* const* d_in, const int* in_sizes, int n_in,
                              void* d_out, int out_size, void* d_ws, size_t ws_size,
                              hipStream_t stream) {
  const float* padded = (const float*)d_in[0];
  const int* lens = (const int*)d_in[1];
  const float* w_in = (const float*)d_in[2];
  const float* b_in = (const float*)d_in[3];
  const float* ln_in_g = (const float*)d_in[4];
  const float* ln_in_b = (const float*)d_in[5];
  const float* pe = (const float*)d_in[6];
  const float* wq = (const float*)d_in[7];
  const float* bq = (const float*)d_in[8];
  const float* wk = (const float*)d_in[9];
  const float* bk = (const float*)d_in[10];
  const float* wv = (const float*)d_in[11];
  const float* bv = (const float*)d_in[12];
  const float* wfc = (const float*)d_in[13];
  const float* bfc = (const float*)d_in[14];
  const float* ln1_g = (const float*)d_in[15];
  const float* ln1_b = (const float*)d_in[16];
  const float* w1 = (const float*)d_in[17];
  const float* b1 = (const float*)d_in[18];
  const float* w2 = (const float*)d_in[19];
  const float* b2 = (const float*)d_in[20];
  const float* ln2_g = (const float*)d_in[21];
  const float* ln2_b = (const float*)d_in[22];

  char* ws = (char*)d_ws;
  size_t off = 0;
  auto alloc = [&](size_t bytes) -> char* {
    char* p = ws + off;
    off += (bytes + 255) & ~(size_t)255;
    return p;
  };
  bh16* WinT  = (bh16*)alloc((size_t)512 * 320 * 2);
  bh16* WqkvT = (bh16*)alloc((size_t)6 * 1536 * 512 * 2);
  bh16* WfcT  = (bh16*)alloc((size_t)6 * 512 * 512 * 2);
  bh16* W1T   = (bh16*)alloc((size_t)6 * 2048 * 512 * 2);
  bh16* W2T   = (bh16*)alloc((size_t)6 * 512 * 2048 * 2);
  float* bqkv = (float*)alloc((size_t)6 * 1536 * 4);
  bh16* xb    = (bh16*)alloc((size_t)8192 * 512 * 2);
  float* xf   = (float*)alloc((size_t)8192 * 512 * 4);
  bh16* qkvb  = (bh16*)alloc((size_t)8192 * 1536 * 2);
  bh16* vt    = (bh16*)alloc((size_t)64 * 64 * 1024 * 2);
  bh16* ob    = (bh16*)alloc((size_t)8192 * 512 * 2);
  float* tmp32 = (float*)alloc((size_t)8192 * 512 * 4);
  bh16* hbuf  = (bh16*)alloc((size_t)8192 * 2048 * 2);
  bh16* padb  = hbuf;  // alias: hbuf is free until w1 GEMM
  if (off > ws_size) return;  // loud failure (output stays poisoned)

  // weights -> bf16 transposed
  tcvt<<<dim3(16, 10, 1), 256, 0, stream>>>(w_in, WinT, 320, 512, 0, 0, 0);
  tcvt<<<dim3(16, 16, 6), 256, 0, stream>>>(wq, WqkvT, 512, 512, 512 * 512, 1536 * 512, 0);
  tcvt<<<dim3(16, 16, 6), 256, 0, stream>>>(wk, WqkvT, 512, 512, 512 * 512, 1536 * 512, 512);
  tcvt<<<dim3(16, 16, 6), 256, 0, stream>>>(wv, WqkvT, 512, 512, 512 * 512, 1536 * 512, 1024);
  tcvt<<<dim3(16, 16, 6), 256, 0, stream>>>(wfc, WfcT, 512, 512, 512 * 512, 512 * 512, 0);
  tcvt<<<dim3(64, 16, 6), 256, 0, stream>>>(w1, W1T, 512, 2048, (long long)512 * 2048, (long long)2048 * 512, 0);
  tcvt<<<dim3(16, 64, 6), 256, 0, stream>>>(w2, W2T, 2048, 512, (long long)2048 * 512, (long long)512 * 2048, 0);
  bcat<<<6, 256, 0, stream>>>(bq, bk, bv, bqkv);
  cvt_in<<<2560, 256, 0, stream>>>(padded, padb, 655360);

  // input projection + LN + PE
  gemm_bt<128, 64, 0, 1><<<dim3(8, 64), 256, 0, stream>>>(
      padb, WinT, b_in, tmp32, 8192, 512, 320);
  ln_pe_k<<<2048, 256, 0, stream>>>(tmp32, ln_in_g, ln_in_b, pe, xf, xb);

  for (int l = 0; l < 6; ++l) {
    gemm_bt<128, 128, 0, 0><<<dim3(12, 64), 256, 0, stream>>>(
        xb, WqkvT + (size_t)l * 1536 * 512, bqkv + l * 1536, qkvb, 8192, 1536, 512);
    vtrans<<<dim3(32, 2, 64), 256, 0, stream>>>(qkvb, vt);
    attn_k<<<1024, 256, 0, stream>>>(qkvb, vt, lens, ob);
    gemm_bt<128, 64, 0, 1><<<dim3(8, 64), 256, 0, stream>>>(
        ob, WfcT + (size_t)l * 512 * 512, bfc + l * 512, tmp32, 8192, 512, 512);
    ln_res_k<<<2048, 256, 0, stream>>>(tmp32, xf, ln1_g + l * 512, ln1_b + l * 512,
                                       lens, xf, xb);
    gemm_bt<128, 128, 1, 0><<<dim3(16, 64), 256, 0, stream>>>(
        xb, W1T + (size_t)l * 2048 * 512, b1 + l * 2048, hbuf, 8192, 2048, 512);
    gemm_bt<128, 64, 0, 1><<<dim3(8, 64), 256, 0, stream>>>(
        hbuf, W2T + (size_t)l * 512 * 2048, b2 + l * 512, tmp32, 8192, 512, 2048);
    float* xfo = (l == 5) ? (float*)d_out : xf;
    ln_res_k<<<2048, 256, 0, stream>>>(tmp32, xf, ln2_g + l * 512, ln2_b + l * 512,
                                       lens, xfo, xb);
  }
}

// Round 6
// 1019.042 us; speedup vs baseline: 1.4696x; 1.0707x over previous
//
#include <hip/hip_runtime.h>
#include <hip/hip_bf16.h>

// ---------------------------------------------------------------------------
// Transformer encoder, B=8 T=1024 D_IN=320 L=6 H=8 DK=DV=64 DM=512 DI=2048.
// R5: staged 2-phase attn (44us) — GEMMs now dominate. w1 FETCH=132MB: A
//   re-fetched by every n-block (XCD round-robin kills L2 reuse).
// R6: (a) XCD super-tile swizzle for all GEMMs — each XCD owns 8 m-panels,
//   co-resident window A+B fits 4MB L2; (b) vtrans fused into qkv epilogue
//   (V-blocks write vt layout directly, skip qkvb V write).
// ---------------------------------------------------------------------------

typedef unsigned short bh16;                                  // bf16 bits
typedef __bf16 bf16x8 __attribute__((ext_vector_type(8)));
typedef float f32x4 __attribute__((ext_vector_type(4)));
typedef unsigned int u32x4 __attribute__((ext_vector_type(4)));
typedef unsigned int u32x2 __attribute__((ext_vector_type(2)));

#define DEVI static __device__ __forceinline__

DEVI bh16 f2bf(float f) {
  union { float f; unsigned u; } x; x.f = f;
  unsigned r = x.u + 0x7fffu + ((x.u >> 16) & 1u);
  return (bh16)(r >> 16);
}
DEVI float bf2f(bh16 u) {
  union { unsigned u; float f; } x; x.u = ((unsigned)u) << 16; return x.f;
}
DEVI bf16x8 ld16(const bh16* p) {
  return __builtin_bit_cast(bf16x8, *(const u32x4*)p);
}
DEVI bf16x8 ld16b(const char* p) {
  return __builtin_bit_cast(bf16x8, *(const u32x4*)p);
}
DEVI f32x4 mfma16(bf16x8 a, bf16x8 b, f32x4 c) {
  return __builtin_amdgcn_mfma_f32_16x16x32_bf16(a, b, c, 0, 0, 0);
}
DEVI void async16(const void* g, void* l) {
  __builtin_amdgcn_global_load_lds(
      (const __attribute__((address_space(1))) void*)g,
      (__attribute__((address_space(3))) void*)l, 16, 0, 0);
}

// ---------------------------------------------------------------------------
// Weight transpose + f32->bf16 convert: in [K][N] f32 -> out [N][K] bf16.
// ---------------------------------------------------------------------------
__global__ __launch_bounds__(256) void tcvt(
    const float* __restrict__ in, bh16* __restrict__ out,
    int K, int N, long long inLS, long long outLS, int rowOff) {
  int l = blockIdx.z;
  in += (size_t)l * inLS;
  out += (size_t)l * outLS + (size_t)rowOff * K;
  __shared__ float t[32][33];
  int n0 = blockIdx.x * 32, k0 = blockIdx.y * 32;
  int tx = threadIdx.x & 31, ty = threadIdx.x >> 5;  // 32 x 8
#pragma unroll
  for (int i = 0; i < 4; i++)
    t[ty + 8 * i][tx] = in[(size_t)(k0 + ty + 8 * i) * N + n0 + tx];
  __syncthreads();
#pragma unroll
  for (int i = 0; i < 4; i++)
    out[(size_t)(n0 + ty + 8 * i) * K + k0 + tx] = f2bf(t[tx][ty + 8 * i]);
}

// bias concat: bq|bk|bv -> [L][1536] f32
__global__ __launch_bounds__(256) void bcat(
    const float* __restrict__ bq, const float* __restrict__ bk,
    const float* __restrict__ bv, float* __restrict__ out) {
  int l = blockIdx.x;
  for (int j = threadIdx.x; j < 1536; j += 256) {
    float v = (j < 512) ? bq[l * 512 + j]
            : (j < 1024) ? bk[l * 512 + j - 512] : bv[l * 512 + j - 1024];
    out[l * 1536 + j] = v;
  }
}

// f32 -> bf16 convert (padded_input)
__global__ __launch_bounds__(256) void cvt_in(
    const float* __restrict__ in, bh16* __restrict__ out, int n4) {
  int i = blockIdx.x * 256 + threadIdx.x;
  if (i < n4) {
    float4 v = ((const float4*)in)[i];
    u32x2 pk;
    pk[0] = (unsigned)f2bf(v.x) | ((unsigned)f2bf(v.y) << 16);
    pk[1] = (unsigned)f2bf(v.z) | ((unsigned)f2bf(v.w) << 16);
    *(u32x2*)(out + (size_t)i * 4) = pk;
  }
}

// ---------------------------------------------------------------------------
// GEMM: C[M][N] = A[M][K](bf16) * Bt[N][K](bf16)^T + bias, m97-style.
// 1-D grid with XCD super-tile swizzle: M=8192 fixed -> 64 m-panels (BM=128),
// 8 per XCD; xcd=p&7, m=(xcd<<3)|(idx&7), n=idx>>3. Co-resident 8m x 8n
// window keeps A+B panels in the XCD's 4MB L2.
// QKV=1: blocks with n0>=1024 are V columns -> write vt[(b*512+vc)][t]
// directly (4 consecutive t per acc = one 8B store); skip qkvb write.
// ---------------------------------------------------------------------------
template <int BM, int BN, int RELU, int OUTF32, int QKV>
__global__ __launch_bounds__(256, 2) void gemm_bt(
    const bh16* __restrict__ A, const bh16* __restrict__ Bt,
    const float* __restrict__ bias, void* __restrict__ Cout,
    bh16* __restrict__ vtOut, int M, int N, int K) {
  constexpr int BK = 64;
  __shared__ __align__(16) bh16 As[BM * BK];
  __shared__ __align__(16) bh16 Bs[BN * BK];
  const int tid = threadIdx.x;
  const int wave = tid >> 6, lane = tid & 63;
  const int lq = lane & 15, grp = lane >> 4;
  const int p = blockIdx.x;
  const int xcd = p & 7, idx = p >> 3;
  const int m0 = (((xcd << 3) | (idx & 7))) * BM;
  const int n0 = (idx >> 3) * BN;
  constexpr int FM = BM / 32, FN = BN / 32;
  const int wr = wave >> 1, wc = wave & 1;
  f32x4 acc[FM][FN] = {};

  const int nk = K / BK;
  for (int kt = 0; kt < nk; ++kt) {
#pragma unroll
    for (int i = 0; i < BM / 32; ++i) {
      int off = i * 4096 + wave * 1024 + lane * 16;
      int row = off >> 7, col = off & 127;
      const char* g = (const char*)A + ((size_t)(m0 + row) * K + kt * BK) * 2 + col;
      async16(g, (char*)As + off);
    }
#pragma unroll
    for (int i = 0; i < BN / 32; ++i) {
      int off = i * 4096 + wave * 1024 + lane * 16;
      int row = off >> 7, col = off & 127;
      const char* g = (const char*)Bt + ((size_t)(n0 + row) * K + kt * BK) * 2 + col;
      async16(g, (char*)Bs + off);
    }
    __syncthreads();
#pragma unroll
    for (int kk = 0; kk < 2; ++kk) {
      bf16x8 af[FM], bfr[FN];
#pragma unroll
      for (int i = 0; i < FM; ++i) {
        int row = wr * (BM / 2) + i * 16 + lq;
        af[i] = ld16(As + row * BK + kk * 32 + grp * 8);
      }
#pragma unroll
      for (int j = 0; j < FN; ++j) {
        int row = wc * (BN / 2) + j * 16 + lq;
        bfr[j] = ld16(Bs + row * BK + kk * 32 + grp * 8);
      }
#pragma unroll
      for (int i = 0; i < FM; ++i)
#pragma unroll
        for (int j = 0; j < FN; ++j)
          acc[i][j] = mfma16(af[i], bfr[j], acc[i][j]);
    }
    __syncthreads();
  }
  // epilogue: D layout col=lane&15, row=(lane>>4)*4+r  [m89-verified]
  if (QKV && n0 >= 1024) {
    // V columns -> vt[(b*512 + vc)][t], 4 consecutive t per acc vector
#pragma unroll
    for (int i = 0; i < FM; ++i) {
#pragma unroll
      for (int j = 0; j < FN; ++j) {
        int col = n0 + wc * (BN / 2) + j * 16 + lq;
        float bv = bias[col];
        int vc = col - 1024;
        int t0 = m0 + wr * (BM / 2) + i * 16 + grp * 4;
        int bb = t0 >> 10, tl = t0 & 1023;
        u32x2 pk;
        pk[0] = (unsigned)f2bf(acc[i][j][0] + bv) |
                ((unsigned)f2bf(acc[i][j][1] + bv) << 16);
        pk[1] = (unsigned)f2bf(acc[i][j][2] + bv) |
                ((unsigned)f2bf(acc[i][j][3] + bv) << 16);
        *(u32x2*)&vtOut[((size_t)(bb * 512 + vc)) * 1024 + tl] = pk;
      }
    }
    return;
  }
#pragma unroll
  for (int i = 0; i < FM; ++i) {
#pragma unroll
    for (int j = 0; j < FN; ++j) {
      int col = n0 + wc * (BN / 2) + j * 16 + lq;
      float bv = bias[col];
#pragma unroll
      for (int r = 0; r < 4; ++r) {
        int row = m0 + wr * (BM / 2) + i * 16 + grp * 4 + r;
        float v = acc[i][j][r] + bv;
        if (RELU) v = fmaxf(v, 0.f);
        if (OUTF32) ((float*)Cout)[(size_t)row * N + col] = v;
        else ((bh16*)Cout)[(size_t)row * N + col] = f2bf(v);
      }
    }
  }
}

// ---------------------------------------------------------------------------
// LayerNorm after input projection: xb/xf = LN(in)*g+b + pe[t]
// ---------------------------------------------------------------------------
__global__ __launch_bounds__(256) void ln_pe_k(
    const float* __restrict__ in, const float* __restrict__ g,
    const float* __restrict__ bta, const float* __restrict__ pe,
    float* __restrict__ xf, bh16* __restrict__ xb) {
  int wave = threadIdx.x >> 6, lane = threadIdx.x & 63;
  int row = blockIdx.x * 4 + wave;
  int t = row & 1023;
  const float* xr = in + (size_t)row * 512 + lane * 8;
  float4 a0 = ((const float4*)xr)[0], a1 = ((const float4*)xr)[1];
  float v[8] = {a0.x, a0.y, a0.z, a0.w, a1.x, a1.y, a1.z, a1.w};
  float s = 0.f, ss = 0.f;
#pragma unroll
  for (int j = 0; j < 8; j++) { s += v[j]; ss += v[j] * v[j]; }
#pragma unroll
  for (int m = 1; m < 64; m <<= 1) { s += __shfl_xor(s, m); ss += __shfl_xor(ss, m); }
  float mu = s * (1.f / 512.f);
  float rstd = rsqrtf(ss * (1.f / 512.f) - mu * mu + 1e-5f);
  int c0 = lane * 8;
  float o[8];
  u32x4 pk;
#pragma unroll
  for (int j = 0; j < 8; j++) {
    int c = c0 + j;
    o[j] = (v[j] - mu) * rstd * g[c] + bta[c] + pe[(size_t)t * 512 + c];
  }
  float4* xo = (float4*)(xf + (size_t)row * 512 + c0);
  xo[0] = make_float4(o[0], o[1], o[2], o[3]);
  xo[1] = make_float4(o[4], o[5], o[6], o[7]);
#pragma unroll
  for (int j = 0; j < 4; j++)
    pk[j] = (unsigned)f2bf(o[2 * j]) | ((unsigned)f2bf(o[2 * j + 1]) << 16);
  *(u32x4*)(xb + (size_t)row * 512 + c0) = pk;
}

// ---------------------------------------------------------------------------
// LayerNorm with residual + pad-mask: out = LN(gout + res)*g+b * nonpad
// ---------------------------------------------------------------------------
__global__ __launch_bounds__(256) void ln_res_k(
    const float* __restrict__ gout, const float* __restrict__ res,
    const float* __restrict__ g, const float* __restrict__ bta,
    const int* __restrict__ lens,
    float* __restrict__ xf, bh16* __restrict__ xb) {
  int wave = threadIdx.x >> 6, lane = threadIdx.x & 63;
  int row = blockIdx.x * 4 + wave;
  int b = row >> 10, t = row & 1023;
  float nonpad = (t < lens[b]) ? 1.f : 0.f;
  const float* xr = gout + (size_t)row * 512 + lane * 8;
  const float* rr = res + (size_t)row * 512 + lane * 8;
  float4 a0 = ((const float4*)xr)[0], a1 = ((const float4*)xr)[1];
  float4 r0 = ((const float4*)rr)[0], r1 = ((const float4*)rr)[1];
  float v[8] = {a0.x + r0.x, a0.y + r0.y, a0.z + r0.z, a0.w + r0.w,
                a1.x + r1.x, a1.y + r1.y, a1.z + r1.z, a1.w + r1.w};
  float s = 0.f, ss = 0.f;
#pragma unroll
  for (int j = 0; j < 8; j++) { s += v[j]; ss += v[j] * v[j]; }
#pragma unroll
  for (int m = 1; m < 64; m <<= 1) { s += __shfl_xor(s, m); ss += __shfl_xor(ss, m); }
  float mu = s * (1.f / 512.f);
  float rstd = rsqrtf(ss * (1.f / 512.f) - mu * mu + 1e-5f);
  int c0 = lane * 8;
  float o[8];
  u32x4 pk;
#pragma unroll
  for (int j = 0; j < 8; j++) {
    int c = c0 + j;
    o[j] = ((v[j] - mu) * rstd * g[c] + bta[c]) * nonpad;
  }
  float4* xo = (float4*)(xf + (size_t)row * 512 + c0);
  xo[0] = make_float4(o[0], o[1], o[2], o[3]);
  xo[1] = make_float4(o[4], o[5], o[6], o[7]);
#pragma unroll
  for (int j = 0; j < 4; j++)
    pk[j] = (unsigned)f2bf(o[2 * j]) | ((unsigned)f2bf(o[2 * j + 1]) << 16);
  *(u32x4*)(xb + (size_t)row * 512 + c0) = pk;
}

// ---------------------------------------------------------------------------
// Fused flash attention, staged 2-phase (unchanged from R5, 44us/layer).
// ---------------------------------------------------------------------------
__global__ __launch_bounds__(256) void attn_k(
    const bh16* __restrict__ qkv, const bh16* __restrict__ vt,
    const int* __restrict__ lens, bh16* __restrict__ o) {
  constexpr int LDP = 72;
  __shared__ __align__(16) char Ks[2][8192];   // [key 0..63][d 0..63] swz
  __shared__ __align__(16) char Vs[2][8192];   // [d 0..63][t 0..63] swz
  __shared__ __align__(16) bh16 P[4][16 * LDP];
  int p = blockIdx.x;
  int xcd = p & 7, s = p >> 3;
  int bh = ((s & 7) << 3) | xcd;
  int qt = s >> 3;
  int b = bh >> 3, h = bh & 7;
  int len = lens[b];
  if (qt * 64 >= len) return;
  int tid = threadIdx.x;
  int wave = tid >> 6, lane = tid & 63;
  int lq = lane & 15, grp = lane >> 4;

  size_t qrow = (size_t)(b * 1024 + qt * 64 + wave * 16 + lq);
  const bh16* Qp = qkv + qrow * 1536 + h * 64;
  bf16x8 qf0 = ld16(Qp + grp * 8);
  bf16x8 qf1 = ld16(Qp + 32 + grp * 8);
  const char* Kbase = (const char*)(qkv + (size_t)(b * 1024) * 1536 + 512 + h * 64);
  const char* Vbase = (const char*)(vt + (size_t)(bh * 64) * 1024);
  bh16* Pw = P[wave];

  f32x4 oacc[4] = {};
  float m = -1e30f, lsum = 0.f;
  int nkb = (len + 63) >> 6;

  auto stage = [&](int buf, int kb) {
#pragma unroll
    for (int t = 0; t < 2; ++t) {
      int off = (tid + t * 256) * 16;
      int row = off >> 7, cb = off & 127;
      int sw = (row & 7) << 4;
      async16(Kbase + (size_t)(kb * 64 + row) * 3072 + (cb ^ sw), Ks[buf] + off);
    }
#pragma unroll
    for (int t = 0; t < 2; ++t) {
      int off = (tid + t * 256) * 16;
      int row = off >> 7, cb = off & 127;
      int sw = (row & 7) << 4;
      async16(Vbase + (size_t)row * 2048 + kb * 128 + (cb ^ sw), Vs[buf] + off);
    }
  };

  stage(0, 0);
  for (int kb = 0; kb < nkb; ++kb) {
    int cur = kb & 1;
    __syncthreads();
    if (kb + 1 < nkb) stage(cur ^ 1, kb + 1);
    int k64 = kb * 64;
    f32x4 st[4];
    __builtin_amdgcn_s_setprio(1);
#pragma unroll
    for (int sv = 0; sv < 4; ++sv) {
      int row = sv * 16 + lq, sw = (row & 7) << 4;
      const char* kp = Ks[cur] + row * 128;
      f32x4 z = {};
      z = mfma16(ld16b(kp + ((grp * 16) ^ sw)), qf0, z);
      z = mfma16(ld16b(kp + ((64 + grp * 16) ^ sw)), qf1, z);
      st[sv] = z;
    }
    __builtin_amdgcn_s_setprio(0);
    float tmax = -1e30f;
    if (k64 + 64 > len) {
#pragma unroll
      for (int sv = 0; sv < 4; ++sv)
#pragma unroll
        for (int r = 0; r < 4; ++r) {
          int key = k64 + sv * 16 + grp * 4 + r;
          float v = st[sv][r] * 0.125f;
          v = (key < len) ? v : -1e30f;
          st[sv][r] = v;
          tmax = fmaxf(tmax, v);
        }
    } else {
#pragma unroll
      for (int sv = 0; sv < 4; ++sv)
#pragma unroll
        for (int r = 0; r < 4; ++r) {
          float v = st[sv][r] * 0.125f;
          st[sv][r] = v;
          tmax = fmaxf(tmax, v);
        }
    }
    tmax = fmaxf(tmax, __shfl_xor(tmax, 16));
    tmax = fmaxf(tmax, __shfl_xor(tmax, 32));
    float newm = fmaxf(m, tmax);
    if (!__all(newm - m <= 8.f)) {
      float sc = __expf(m - newm);
      m = newm;
      lsum *= sc;
#pragma unroll
      for (int r = 0; r < 4; ++r) {
        float scr = __shfl(sc, grp * 4 + r);
#pragma unroll
        for (int dt = 0; dt < 4; ++dt) oacc[dt][r] *= scr;
      }
    }
    float rs = 0.f;
#pragma unroll
    for (int sv = 0; sv < 4; ++sv) {
      float p0 = __expf(st[sv][0] - m), p1 = __expf(st[sv][1] - m);
      float p2 = __expf(st[sv][2] - m), p3 = __expf(st[sv][3] - m);
      rs += (p0 + p1) + (p2 + p3);
      u32x2 pk;
      pk[0] = (unsigned)f2bf(p0) | ((unsigned)f2bf(p1) << 16);
      pk[1] = (unsigned)f2bf(p2) | ((unsigned)f2bf(p3) << 16);
      *(u32x2*)&Pw[lq * LDP + sv * 16 + grp * 4] = pk;
    }
    rs += __shfl_xor(rs, 16);
    rs += __shfl_xor(rs, 32);
    lsum += rs;
#pragma unroll
    for (int kk = 0; kk < 2; ++kk) {
      bf16x8 pa = ld16(Pw + lq * LDP + kk * 32 + grp * 8);
      __builtin_amdgcn_s_setprio(1);
#pragma unroll
      for (int dt = 0; dt < 4; ++dt) {
        int row = dt * 16 + lq, sw = (row & 7) << 4;
        bf16x8 vfr = ld16b(Vs[cur] + row * 128 + ((kk * 64 + grp * 16) ^ sw));
        oacc[dt] = mfma16(pa, vfr, oacc[dt]);
      }
      __builtin_amdgcn_s_setprio(0);
    }
  }
#pragma unroll
  for (int r = 0; r < 4; ++r) {
    float li = __shfl(lsum, grp * 4 + r);
    float inv = 1.f / li;
    int row = qt * 64 + wave * 16 + grp * 4 + r;
    bh16* orow = o + (size_t)(b * 1024 + row) * 512 + h * 64;
#pragma unroll
    for (int dt = 0; dt < 4; ++dt) orow[dt * 16 + lq] = f2bf(oacc[dt][r] * inv);
  }
}

// ---------------------------------------------------------------------------
// host
// ---------------------------------------------------------------------------
extern "C" void kernel_launch(void* const* d_in, const int* in_sizes, int n_in,
                              void* d_out, int out_size, void* d_ws, size_t ws_size,
                              hipStream_t stream) {
  const float* padded = (const float*)d_in[0];
  const int* lens = (const int*)d_in[1];
  const float* w_in = (const float*)d_in[2];
  const float* b_in = (const float*)d_in[3];
  const float* ln_in_g = (const float*)d_in[4];
  const float* ln_in_b = (const float*)d_in[5];
  const float* pe = (const float*)d_in[6];
  const float* wq = (const float*)d_in[7];
  const float* bq = (const float*)d_in[8];
  const float* wk = (const float*)d_in[9];
  const float* bk = (const float*)d_in[10];
  const float* wv = (const float*)d_in[11];
  const float* bv = (const float*)d_in[12];
  const float* wfc = (const float*)d_in[13];
  const float* bfc = (const float*)d_in[14];
  const float* ln1_g = (const float*)d_in[15];
  const float* ln1_b = (const float*)d_in[16];
  const float* w1 = (const float*)d_in[17];
  const float* b1 = (const float*)d_in[18];
  const float* w2 = (const float*)d_in[19];
  const float* b2 = (const float*)d_in[20];
  const float* ln2_g = (const float*)d_in[21];
  const float* ln2_b = (const float*)d_in[22];

  char* ws = (char*)d_ws;
  size_t off = 0;
  auto alloc = [&](size_t bytes) -> char* {
    char* p = ws + off;
    off += (bytes + 255) & ~(size_t)255;
    return p;
  };
  bh16* WinT  = (bh16*)alloc((size_t)512 * 320 * 2);
  bh16* WqkvT = (bh16*)alloc((size_t)6 * 1536 * 512 * 2);
  bh16* WfcT  = (bh16*)alloc((size_t)6 * 512 * 512 * 2);
  bh16* W1T   = (bh16*)alloc((size_t)6 * 2048 * 512 * 2);
  bh16* W2T   = (bh16*)alloc((size_t)6 * 512 * 2048 * 2);
  float* bqkv = (float*)alloc((size_t)6 * 1536 * 4);
  bh16* xb    = (bh16*)alloc((size_t)8192 * 512 * 2);
  float* xf   = (float*)alloc((size_t)8192 * 512 * 4);
  bh16* qkvb  = (bh16*)alloc((size_t)8192 * 1536 * 2);
  bh16* vt    = (bh16*)alloc((size_t)64 * 64 * 1024 * 2);
  bh16* ob    = (bh16*)alloc((size_t)8192 * 512 * 2);
  float* tmp32 = (float*)alloc((size_t)8192 * 512 * 4);
  bh16* hbuf  = (bh16*)alloc((size_t)8192 * 2048 * 2);
  bh16* padb  = hbuf;  // alias: hbuf is free until w1 GEMM
  if (off > ws_size) return;  // loud failure (output stays poisoned)

  // weights -> bf16 transposed
  tcvt<<<dim3(16, 10, 1), 256, 0, stream>>>(w_in, WinT, 320, 512, 0, 0, 0);
  tcvt<<<dim3(16, 16, 6), 256, 0, stream>>>(wq, WqkvT, 512, 512, 512 * 512, 1536 * 512, 0);
  tcvt<<<dim3(16, 16, 6), 256, 0, stream>>>(wk, WqkvT, 512, 512, 512 * 512, 1536 * 512, 512);
  tcvt<<<dim3(16, 16, 6), 256, 0, stream>>>(wv, WqkvT, 512, 512, 512 * 512, 1536 * 512, 1024);
  tcvt<<<dim3(16, 16, 6), 256, 0, stream>>>(wfc, WfcT, 512, 512, 512 * 512, 512 * 512, 0);
  tcvt<<<dim3(64, 16, 6), 256, 0, stream>>>(w1, W1T, 512, 2048, (long long)512 * 2048, (long long)2048 * 512, 0);
  tcvt<<<dim3(16, 64, 6), 256, 0, stream>>>(w2, W2T, 2048, 512, (long long)2048 * 512, (long long)512 * 2048, 0);
  bcat<<<6, 256, 0, stream>>>(bq, bk, bv, bqkv);
  cvt_in<<<2560, 256, 0, stream>>>(padded, padb, 655360);

  // input projection + LN + PE   (M=8192 -> 64 m-panels; grid = nN*64, 1-D)
  gemm_bt<128, 64, 0, 1, 0><<<512, 256, 0, stream>>>(
      padb, WinT, b_in, tmp32, nullptr, 8192, 512, 320);
  ln_pe_k<<<2048, 256, 0, stream>>>(tmp32, ln_in_g, ln_in_b, pe, xf, xb);

  for (int l = 0; l < 6; ++l) {
    gemm_bt<128, 128, 0, 0, 1><<<768, 256, 0, stream>>>(
        xb, WqkvT + (size_t)l * 1536 * 512, bqkv + l * 1536, qkvb, vt,
        8192, 1536, 512);
    attn_k<<<1024, 256, 0, stream>>>(qkvb, vt, lens, ob);
    gemm_bt<128, 64, 0, 1, 0><<<512, 256, 0, stream>>>(
        ob, WfcT + (size_t)l * 512 * 512, bfc + l * 512, tmp32, nullptr,
        8192, 512, 512);
    ln_res_k<<<2048, 256, 0, stream>>>(tmp32, xf, ln1_g + l * 512, ln1_b + l * 512,
                                       lens, xf, xb);
    gemm_bt<128, 128, 1, 0, 0><<<1024, 256, 0, stream>>>(
        xb, W1T + (size_t)l * 2048 * 512, b1 + l * 2048, hbuf, nullptr,
        8192, 2048, 512);
    gemm_bt<128, 64, 0, 1, 0><<<512, 256, 0, stream>>>(
        hbuf, W2T + (size_t)l * 512 * 2048, b2 + l * 512, tmp32, nullptr,
        8192, 512, 2048);
    float* xfo = (l == 5) ? (float*)d_out : xf;
    ln_res_k<<<2048, 256, 0, stream>>>(tmp32, xf, ln2_g + l * 512, ln2_b + l * 512,
                                       lens, xfo, xb);
  }
}

// Round 7
// 941.581 us; speedup vs baseline: 1.5904x; 1.0823x over previous
//
#include <hip/hip_runtime.h>
#include <hip/hip_bf16.h>

// ---------------------------------------------------------------------------
// Transformer encoder, B=8 T=1024 D_IN=320 L=6 H=8 DK=DV=64 DM=512 DI=2048.
// R6: XCD super-tile GEMM swizzle + vtrans fused into qkv epilogue -> 1019us.
// R7: (a) attn 8-wave blocks (QBLK=128): same K/V staging + 1 barrier/iter
//   amortized over 2x the q-rows; per-wave state unchanged (VGPR 68); LDS
//   50KB -> 3 blocks/CU. (b) fc/w2 GEMMs write bf16; ln_res reads bf16 gout
//   (LN kernels are BW-bound; cut bytes).
// ---------------------------------------------------------------------------

typedef unsigned short bh16;                                  // bf16 bits
typedef __bf16 bf16x8 __attribute__((ext_vector_type(8)));
typedef float f32x4 __attribute__((ext_vector_type(4)));
typedef unsigned int u32x4 __attribute__((ext_vector_type(4)));
typedef unsigned int u32x2 __attribute__((ext_vector_type(2)));

#define DEVI static __device__ __forceinline__

DEVI bh16 f2bf(float f) {
  union { float f; unsigned u; } x; x.f = f;
  unsigned r = x.u + 0x7fffu + ((x.u >> 16) & 1u);
  return (bh16)(r >> 16);
}
DEVI float bf2f(bh16 u) {
  union { unsigned u; float f; } x; x.u = ((unsigned)u) << 16; return x.f;
}
DEVI bf16x8 ld16(const bh16* p) {
  return __builtin_bit_cast(bf16x8, *(const u32x4*)p);
}
DEVI bf16x8 ld16b(const char* p) {
  return __builtin_bit_cast(bf16x8, *(const u32x4*)p);
}
DEVI f32x4 mfma16(bf16x8 a, bf16x8 b, f32x4 c) {
  return __builtin_amdgcn_mfma_f32_16x16x32_bf16(a, b, c, 0, 0, 0);
}
DEVI void async16(const void* g, void* l) {
  __builtin_amdgcn_global_load_lds(
      (const __attribute__((address_space(1))) void*)g,
      (__attribute__((address_space(3))) void*)l, 16, 0, 0);
}

// ---------------------------------------------------------------------------
// Weight transpose + f32->bf16 convert: in [K][N] f32 -> out [N][K] bf16.
// ---------------------------------------------------------------------------
__global__ __launch_bounds__(256) void tcvt(
    const float* __restrict__ in, bh16* __restrict__ out,
    int K, int N, long long inLS, long long outLS, int rowOff) {
  int l = blockIdx.z;
  in += (size_t)l * inLS;
  out += (size_t)l * outLS + (size_t)rowOff * K;
  __shared__ float t[32][33];
  int n0 = blockIdx.x * 32, k0 = blockIdx.y * 32;
  int tx = threadIdx.x & 31, ty = threadIdx.x >> 5;  // 32 x 8
#pragma unroll
  for (int i = 0; i < 4; i++)
    t[ty + 8 * i][tx] = in[(size_t)(k0 + ty + 8 * i) * N + n0 + tx];
  __syncthreads();
#pragma unroll
  for (int i = 0; i < 4; i++)
    out[(size_t)(n0 + ty + 8 * i) * K + k0 + tx] = f2bf(t[tx][ty + 8 * i]);
}

// bias concat: bq|bk|bv -> [L][1536] f32
__global__ __launch_bounds__(256) void bcat(
    const float* __restrict__ bq, const float* __restrict__ bk,
    const float* __restrict__ bv, float* __restrict__ out) {
  int l = blockIdx.x;
  for (int j = threadIdx.x; j < 1536; j += 256) {
    float v = (j < 512) ? bq[l * 512 + j]
            : (j < 1024) ? bk[l * 512 + j - 512] : bv[l * 512 + j - 1024];
    out[l * 1536 + j] = v;
  }
}

// f32 -> bf16 convert (padded_input)
__global__ __launch_bounds__(256) void cvt_in(
    const float* __restrict__ in, bh16* __restrict__ out, int n4) {
  int i = blockIdx.x * 256 + threadIdx.x;
  if (i < n4) {
    float4 v = ((const float4*)in)[i];
    u32x2 pk;
    pk[0] = (unsigned)f2bf(v.x) | ((unsigned)f2bf(v.y) << 16);
    pk[1] = (unsigned)f2bf(v.z) | ((unsigned)f2bf(v.w) << 16);
    *(u32x2*)(out + (size_t)i * 4) = pk;
  }
}

// ---------------------------------------------------------------------------
// GEMM: C[M][N] = A[M][K](bf16) * Bt[N][K](bf16)^T + bias, m97-style.
// 1-D grid, XCD super-tile swizzle (8 m-panels per XCD -> A+B window in L2).
// QKV=1: n0>=1024 blocks write vt[(b*512+vc)][t] directly.
// ---------------------------------------------------------------------------
template <int BM, int BN, int RELU, int OUTF32, int QKV>
__global__ __launch_bounds__(256, 2) void gemm_bt(
    const bh16* __restrict__ A, const bh16* __restrict__ Bt,
    const float* __restrict__ bias, void* __restrict__ Cout,
    bh16* __restrict__ vtOut, int M, int N, int K) {
  constexpr int BK = 64;
  __shared__ __align__(16) bh16 As[BM * BK];
  __shared__ __align__(16) bh16 Bs[BN * BK];
  const int tid = threadIdx.x;
  const int wave = tid >> 6, lane = tid & 63;
  const int lq = lane & 15, grp = lane >> 4;
  const int p = blockIdx.x;
  const int xcd = p & 7, idx = p >> 3;
  const int m0 = (((xcd << 3) | (idx & 7))) * BM;
  const int n0 = (idx >> 3) * BN;
  constexpr int FM = BM / 32, FN = BN / 32;
  const int wr = wave >> 1, wc = wave & 1;
  f32x4 acc[FM][FN] = {};

  const int nk = K / BK;
  for (int kt = 0; kt < nk; ++kt) {
#pragma unroll
    for (int i = 0; i < BM / 32; ++i) {
      int off = i * 4096 + wave * 1024 + lane * 16;
      int row = off >> 7, col = off & 127;
      const char* g = (const char*)A + ((size_t)(m0 + row) * K + kt * BK) * 2 + col;
      async16(g, (char*)As + off);
    }
#pragma unroll
    for (int i = 0; i < BN / 32; ++i) {
      int off = i * 4096 + wave * 1024 + lane * 16;
      int row = off >> 7, col = off & 127;
      const char* g = (const char*)Bt + ((size_t)(n0 + row) * K + kt * BK) * 2 + col;
      async16(g, (char*)Bs + off);
    }
    __syncthreads();
#pragma unroll
    for (int kk = 0; kk < 2; ++kk) {
      bf16x8 af[FM], bfr[FN];
#pragma unroll
      for (int i = 0; i < FM; ++i) {
        int row = wr * (BM / 2) + i * 16 + lq;
        af[i] = ld16(As + row * BK + kk * 32 + grp * 8);
      }
#pragma unroll
      for (int j = 0; j < FN; ++j) {
        int row = wc * (BN / 2) + j * 16 + lq;
        bfr[j] = ld16(Bs + row * BK + kk * 32 + grp * 8);
      }
#pragma unroll
      for (int i = 0; i < FM; ++i)
#pragma unroll
        for (int j = 0; j < FN; ++j)
          acc[i][j] = mfma16(af[i], bfr[j], acc[i][j]);
    }
    __syncthreads();
  }
  // epilogue: D layout col=lane&15, row=(lane>>4)*4+r  [m89-verified]
  if (QKV && n0 >= 1024) {
#pragma unroll
    for (int i = 0; i < FM; ++i) {
#pragma unroll
      for (int j = 0; j < FN; ++j) {
        int col = n0 + wc * (BN / 2) + j * 16 + lq;
        float bv = bias[col];
        int vc = col - 1024;
        int t0 = m0 + wr * (BM / 2) + i * 16 + grp * 4;
        int bb = t0 >> 10, tl = t0 & 1023;
        u32x2 pk;
        pk[0] = (unsigned)f2bf(acc[i][j][0] + bv) |
                ((unsigned)f2bf(acc[i][j][1] + bv) << 16);
        pk[1] = (unsigned)f2bf(acc[i][j][2] + bv) |
                ((unsigned)f2bf(acc[i][j][3] + bv) << 16);
        *(u32x2*)&vtOut[((size_t)(bb * 512 + vc)) * 1024 + tl] = pk;
      }
    }
    return;
  }
#pragma unroll
  for (int i = 0; i < FM; ++i) {
#pragma unroll
    for (int j = 0; j < FN; ++j) {
      int col = n0 + wc * (BN / 2) + j * 16 + lq;
      float bv = bias[col];
#pragma unroll
      for (int r = 0; r < 4; ++r) {
        int row = m0 + wr * (BM / 2) + i * 16 + grp * 4 + r;
        float v = acc[i][j][r] + bv;
        if (RELU) v = fmaxf(v, 0.f);
        if (OUTF32) ((float*)Cout)[(size_t)row * N + col] = v;
        else ((bh16*)Cout)[(size_t)row * N + col] = f2bf(v);
      }
    }
  }
}

// ---------------------------------------------------------------------------
// LayerNorm after input projection: xb/xf = LN(in)*g+b + pe[t]  (f32 in)
// ---------------------------------------------------------------------------
__global__ __launch_bounds__(256) void ln_pe_k(
    const float* __restrict__ in, const float* __restrict__ g,
    const float* __restrict__ bta, const float* __restrict__ pe,
    float* __restrict__ xf, bh16* __restrict__ xb) {
  int wave = threadIdx.x >> 6, lane = threadIdx.x & 63;
  int row = blockIdx.x * 4 + wave;
  int t = row & 1023;
  const float* xr = in + (size_t)row * 512 + lane * 8;
  float4 a0 = ((const float4*)xr)[0], a1 = ((const float4*)xr)[1];
  float v[8] = {a0.x, a0.y, a0.z, a0.w, a1.x, a1.y, a1.z, a1.w};
  float s = 0.f, ss = 0.f;
#pragma unroll
  for (int j = 0; j < 8; j++) { s += v[j]; ss += v[j] * v[j]; }
#pragma unroll
  for (int m = 1; m < 64; m <<= 1) { s += __shfl_xor(s, m); ss += __shfl_xor(ss, m); }
  float mu = s * (1.f / 512.f);
  float rstd = rsqrtf(ss * (1.f / 512.f) - mu * mu + 1e-5f);
  int c0 = lane * 8;
  float o[8];
  u32x4 pk;
#pragma unroll
  for (int j = 0; j < 8; j++) {
    int c = c0 + j;
    o[j] = (v[j] - mu) * rstd * g[c] + bta[c] + pe[(size_t)t * 512 + c];
  }
  float4* xo = (float4*)(xf + (size_t)row * 512 + c0);
  xo[0] = make_float4(o[0], o[1], o[2], o[3]);
  xo[1] = make_float4(o[4], o[5], o[6], o[7]);
#pragma unroll
  for (int j = 0; j < 4; j++)
    pk[j] = (unsigned)f2bf(o[2 * j]) | ((unsigned)f2bf(o[2 * j + 1]) << 16);
  *(u32x4*)(xb + (size_t)row * 512 + c0) = pk;
}

// ---------------------------------------------------------------------------
// LayerNorm with residual + pad-mask: out = LN(gout(bf16) + res)*g+b * nonpad
// ---------------------------------------------------------------------------
__global__ __launch_bounds__(256) void ln_res_k(
    const bh16* __restrict__ gout, const float* __restrict__ res,
    const float* __restrict__ g, const float* __restrict__ bta,
    const int* __restrict__ lens,
    float* __restrict__ xf, bh16* __restrict__ xb) {
  int wave = threadIdx.x >> 6, lane = threadIdx.x & 63;
  int row = blockIdx.x * 4 + wave;
  int b = row >> 10, t = row & 1023;
  float nonpad = (t < lens[b]) ? 1.f : 0.f;
  int c0 = lane * 8;
  u32x4 graw = *(const u32x4*)(gout + (size_t)row * 512 + c0);
  const float* rr = res + (size_t)row * 512 + c0;
  float4 r0 = ((const float4*)rr)[0], r1 = ((const float4*)rr)[1];
  float v[8];
#pragma unroll
  for (int j = 0; j < 4; j++) {
    v[2 * j] = bf2f((bh16)(graw[j] & 0xffffu));
    v[2 * j + 1] = bf2f((bh16)(graw[j] >> 16));
  }
  v[0] += r0.x; v[1] += r0.y; v[2] += r0.z; v[3] += r0.w;
  v[4] += r1.x; v[5] += r1.y; v[6] += r1.z; v[7] += r1.w;
  float s = 0.f, ss = 0.f;
#pragma unroll
  for (int j = 0; j < 8; j++) { s += v[j]; ss += v[j] * v[j]; }
#pragma unroll
  for (int m = 1; m < 64; m <<= 1) { s += __shfl_xor(s, m); ss += __shfl_xor(ss, m); }
  float mu = s * (1.f / 512.f);
  float rstd = rsqrtf(ss * (1.f / 512.f) - mu * mu + 1e-5f);
  float o[8];
  u32x4 pk;
#pragma unroll
  for (int j = 0; j < 8; j++) {
    int c = c0 + j;
    o[j] = ((v[j] - mu) * rstd * g[c] + bta[c]) * nonpad;
  }
  float4* xo = (float4*)(xf + (size_t)row * 512 + c0);
  xo[0] = make_float4(o[0], o[1], o[2], o[3]);
  xo[1] = make_float4(o[4], o[5], o[6], o[7]);
#pragma unroll
  for (int j = 0; j < 4; j++)
    pk[j] = (unsigned)f2bf(o[2 * j]) | ((unsigned)f2bf(o[2 * j + 1]) << 16);
  *(u32x4*)(xb + (size_t)row * 512 + c0) = pk;
}

// ---------------------------------------------------------------------------
// Fused flash attention, staged 2-phase, 8 waves x 16 q = 128 q-rows/block.
// grid 512 = {8 qt x 64 bh}, XCD-swizzled (same bh -> same XCD). Per 64-key
// iter: sync -> stage(next K[64][64]+Vt[64][64], T2 swizzle) -> compute.
// Staging+barrier amortized over 8 waves; per-wave state as R5 (VGPR ~68).
// ---------------------------------------------------------------------------
__global__ __launch_bounds__(512) void attn_k(
    const bh16* __restrict__ qkv, const bh16* __restrict__ vt,
    const int* __restrict__ lens, bh16* __restrict__ o) {
  constexpr int LDP = 72;
  __shared__ __align__(16) char Ks[2][8192];   // [key 0..63][d 0..63] swz
  __shared__ __align__(16) char Vs[2][8192];   // [d 0..63][t 0..63] swz
  __shared__ __align__(16) bh16 P[8][16 * LDP];
  int p = blockIdx.x;
  int xcd = p & 7, s = p >> 3;          // s in 0..63
  int bh = ((s & 7) << 3) | xcd;
  int qt = s >> 3;                      // 0..7
  int b = bh >> 3, h = bh & 7;
  int len = lens[b];
  if (qt * 128 >= len) return;
  int tid = threadIdx.x;
  int wave = tid >> 6, lane = tid & 63;
  int lq = lane & 15, grp = lane >> 4;

  size_t qrow = (size_t)(b * 1024 + qt * 128 + wave * 16 + lq);
  const bh16* Qp = qkv + qrow * 1536 + h * 64;
  bf16x8 qf0 = ld16(Qp + grp * 8);
  bf16x8 qf1 = ld16(Qp + 32 + grp * 8);
  const char* Kbase = (const char*)(qkv + (size_t)(b * 1024) * 1536 + 512 + h * 64);
  const char* Vbase = (const char*)(vt + (size_t)(bh * 64) * 1024);
  bh16* Pw = P[wave];

  f32x4 oacc[4] = {};
  float m = -1e30f, lsum = 0.f;
  int nkb = (len + 63) >> 6;

  // stage: 512 threads x 16B = one 8KB tile per pass; source inverse-swizzled
  auto stage = [&](int buf, int kb) {
    int off = tid * 16;
    int row = off >> 7, cb = off & 127;
    int sw = (row & 7) << 4;
    async16(Kbase + (size_t)(kb * 64 + row) * 3072 + (cb ^ sw), Ks[buf] + off);
    async16(Vbase + (size_t)row * 2048 + kb * 128 + (cb ^ sw), Vs[buf] + off);
  };

  stage(0, 0);
  for (int kb = 0; kb < nkb; ++kb) {
    int cur = kb & 1;
    __syncthreads();                  // stage(kb) complete; prev readers done
    if (kb + 1 < nkb) stage(cur ^ 1, kb + 1);
    int k64 = kb * 64;
    f32x4 st[4];
    __builtin_amdgcn_s_setprio(1);
#pragma unroll
    for (int sv = 0; sv < 4; ++sv) {
      int row = sv * 16 + lq, sw = (row & 7) << 4;
      const char* kp = Ks[cur] + row * 128;
      f32x4 z = {};
      z = mfma16(ld16b(kp + ((grp * 16) ^ sw)), qf0, z);
      z = mfma16(ld16b(kp + ((64 + grp * 16) ^ sw)), qf1, z);
      st[sv] = z;
    }
    __builtin_amdgcn_s_setprio(0);
    float tmax = -1e30f;
    if (k64 + 64 > len) {
#pragma unroll
      for (int sv = 0; sv < 4; ++sv)
#pragma unroll
        for (int r = 0; r < 4; ++r) {
          int key = k64 + sv * 16 + grp * 4 + r;
          float v = st[sv][r] * 0.125f;
          v = (key < len) ? v : -1e30f;
          st[sv][r] = v;
          tmax = fmaxf(tmax, v);
        }
    } else {
#pragma unroll
      for (int sv = 0; sv < 4; ++sv)
#pragma unroll
        for (int r = 0; r < 4; ++r) {
          float v = st[sv][r] * 0.125f;
          st[sv][r] = v;
          tmax = fmaxf(tmax, v);
        }
    }
    tmax = fmaxf(tmax, __shfl_xor(tmax, 16));
    tmax = fmaxf(tmax, __shfl_xor(tmax, 32));
    float newm = fmaxf(m, tmax);
    if (!__all(newm - m <= 8.f)) {
      float sc = __expf(m - newm);
      m = newm;
      lsum *= sc;
#pragma unroll
      for (int r = 0; r < 4; ++r) {
        float scr = __shfl(sc, grp * 4 + r);
#pragma unroll
        for (int dt = 0; dt < 4; ++dt) oacc[dt][r] *= scr;
      }
    }
    float rs = 0.f;
#pragma unroll
    for (int sv = 0; sv < 4; ++sv) {
      float p0 = __expf(st[sv][0] - m), p1 = __expf(st[sv][1] - m);
      float p2 = __expf(st[sv][2] - m), p3 = __expf(st[sv][3] - m);
      rs += (p0 + p1) + (p2 + p3);
      u32x2 pk;
      pk[0] = (unsigned)f2bf(p0) | ((unsigned)f2bf(p1) << 16);
      pk[1] = (unsigned)f2bf(p2) | ((unsigned)f2bf(p3) << 16);
      *(u32x2*)&Pw[lq * LDP + sv * 16 + grp * 4] = pk;
    }
    rs += __shfl_xor(rs, 16);
    rs += __shfl_xor(rs, 32);
    lsum += rs;
#pragma unroll
    for (int kk = 0; kk < 2; ++kk) {
      bf16x8 pa = ld16(Pw + lq * LDP + kk * 32 + grp * 8);
      __builtin_amdgcn_s_setprio(1);
#pragma unroll
      for (int dt = 0; dt < 4; ++dt) {
        int row = dt * 16 + lq, sw = (row & 7) << 4;
        bf16x8 vfr = ld16b(Vs[cur] + row * 128 + ((kk * 64 + grp * 16) ^ sw));
        oacc[dt] = mfma16(pa, vfr, oacc[dt]);
      }
      __builtin_amdgcn_s_setprio(0);
    }
  }
#pragma unroll
  for (int r = 0; r < 4; ++r) {
    float li = __shfl(lsum, grp * 4 + r);
    float inv = 1.f / li;
    int row = qt * 128 + wave * 16 + grp * 4 + r;
    bh16* orow = o + (size_t)(b * 1024 + row) * 512 + h * 64;
#pragma unroll
    for (int dt = 0; dt < 4; ++dt) orow[dt * 16 + lq] = f2bf(oacc[dt][r] * inv);
  }
}

// ---------------------------------------------------------------------------
// host
// ---------------------------------------------------------------------------
extern "C" void kernel_launch(void* const* d_in, const int* in_sizes, int n_in,
                              void* d_out, int out_size, void* d_ws, size_t ws_size,
                              hipStream_t stream) {
  const float* padded = (const float*)d_in[0];
  const int* lens = (const int*)d_in[1];
  const float* w_in = (const float*)d_in[2];
  const float* b_in = (const float*)d_in[3];
  const float* ln_in_g = (const float*)d_in[4];
  const float* ln_in_b = (const float*)d_in[5];
  const float* pe = (const float*)d_in[6];
  const float* wq = (const float*)d_in[7];
  const float* bq = (const float*)d_in[8];
  const float* wk = (const float*)d_in[9];
  const float* bk = (const float*)d_in[10];
  const float* wv = (const float*)d_in[11];
  const float* bv = (const float*)d_in[12];
  const float* wfc = (const float*)d_in[13];
  const float* bfc = (const float*)d_in[14];
  const float* ln1_g = (const float*)d_in[15];
  const float* ln1_b = (const float*)d_in[16];
  const float* w1 = (const float*)d_in[17];
  const float* b1 = (const float*)d_in[18];
  const float* w2 = (const float*)d_in[19];
  const float* b2 = (const float*)d_in[20];
  const float* ln2_g = (const float*)d_in[21];
  const float* ln2_b = (const float*)d_in[22];

  char* ws = (char*)d_ws;
  size_t off = 0;
  auto alloc = [&](size_t bytes) -> char* {
    char* p = ws + off;
    off += (bytes + 255) & ~(size_t)255;
    return p;
  };
  bh16* WinT  = (bh16*)alloc((size_t)512 * 320 * 2);
  bh16* WqkvT = (bh16*)alloc((size_t)6 * 1536 * 512 * 2);
  bh16* WfcT  = (bh16*)alloc((size_t)6 * 512 * 512 * 2);
  bh16* W1T   = (bh16*)alloc((size_t)6 * 2048 * 512 * 2);
  bh16* W2T   = (bh16*)alloc((size_t)6 * 512 * 2048 * 2);
  float* bqkv = (float*)alloc((size_t)6 * 1536 * 4);
  bh16* xb    = (bh16*)alloc((size_t)8192 * 512 * 2);
  float* xf   = (float*)alloc((size_t)8192 * 512 * 4);
  bh16* qkvb  = (bh16*)alloc((size_t)8192 * 1536 * 2);
  bh16* vt    = (bh16*)alloc((size_t)64 * 64 * 1024 * 2);
  bh16* ob    = (bh16*)alloc((size_t)8192 * 512 * 2);
  float* tmp32 = (float*)alloc((size_t)8192 * 512 * 4);
  bh16* tmp16 = (bh16*)alloc((size_t)8192 * 512 * 2);
  bh16* hbuf  = (bh16*)alloc((size_t)8192 * 2048 * 2);
  bh16* padb  = hbuf;  // alias: hbuf is free until w1 GEMM
  if (off > ws_size) return;  // loud failure (output stays poisoned)

  // weights -> bf16 transposed
  tcvt<<<dim3(16, 10, 1), 256, 0, stream>>>(w_in, WinT, 320, 512, 0, 0, 0);
  tcvt<<<dim3(16, 16, 6), 256, 0, stream>>>(wq, WqkvT, 512, 512, 512 * 512, 1536 * 512, 0);
  tcvt<<<dim3(16, 16, 6), 256, 0, stream>>>(wk, WqkvT, 512, 512, 512 * 512, 1536 * 512, 512);
  tcvt<<<dim3(16, 16, 6), 256, 0, stream>>>(wv, WqkvT, 512, 512, 512 * 512, 1536 * 512, 1024);
  tcvt<<<dim3(16, 16, 6), 256, 0, stream>>>(wfc, WfcT, 512, 512, 512 * 512, 512 * 512, 0);
  tcvt<<<dim3(64, 16, 6), 256, 0, stream>>>(w1, W1T, 512, 2048, (long long)512 * 2048, (long long)2048 * 512, 0);
  tcvt<<<dim3(16, 64, 6), 256, 0, stream>>>(w2, W2T, 2048, 512, (long long)2048 * 512, (long long)512 * 2048, 0);
  bcat<<<6, 256, 0, stream>>>(bq, bk, bv, bqkv);
  cvt_in<<<2560, 256, 0, stream>>>(padded, padb, 655360);

  // input projection + LN + PE
  gemm_bt<128, 64, 0, 1, 0><<<512, 256, 0, stream>>>(
      padb, WinT, b_in, tmp32, nullptr, 8192, 512, 320);
  ln_pe_k<<<2048, 256, 0, stream>>>(tmp32, ln_in_g, ln_in_b, pe, xf, xb);

  for (int l = 0; l < 6; ++l) {
    gemm_bt<128, 128, 0, 0, 1><<<768, 256, 0, stream>>>(
        xb, WqkvT + (size_t)l * 1536 * 512, bqkv + l * 1536, qkvb, vt,
        8192, 1536, 512);
    attn_k<<<512, 512, 0, stream>>>(qkvb, vt, lens, ob);
    gemm_bt<128, 64, 0, 0, 0><<<512, 256, 0, stream>>>(
        ob, WfcT + (size_t)l * 512 * 512, bfc + l * 512, tmp16, nullptr,
        8192, 512, 512);
    ln_res_k<<<2048, 256, 0, stream>>>(tmp16, xf, ln1_g + l * 512, ln1_b + l * 512,
                                       lens, xf, xb);
    gemm_bt<128, 128, 1, 0, 0><<<1024, 256, 0, stream>>>(
        xb, W1T + (size_t)l * 2048 * 512, b1 + l * 2048, hbuf, nullptr,
        8192, 2048, 512);
    gemm_bt<128, 64, 0, 0, 0><<<512, 256, 0, stream>>>(
        hbuf, W2T + (size_t)l * 512 * 2048, b2 + l * 512, tmp16, nullptr,
        8192, 512, 2048);
    float* xfo = (l == 5) ? (float*)d_out : xf;
    ln_res_k<<<2048, 256, 0, stream>>>(tmp16, xf, ln2_g + l * 512, ln2_b + l * 512,
                                       lens, xfo, xb);
  }
}

// Round 8
// 859.086 us; speedup vs baseline: 1.7432x; 1.0960x over previous
//
#include <hip/hip_runtime.h>
#include <hip/hip_bf16.h>

// ---------------------------------------------------------------------------
// Transformer encoder, B=8 T=1024 D_IN=320 L=6 H=8 DK=DV=64 DM=512 DI=2048.
// R7: attn 8-wave staged blocks + bf16 LN inputs -> 942us; GEMMs now top
//   (39us, MfmaUtil 15%, bank-conflict ~38% of cycles, zero stage overlap).
// R8: GEMM K-loop restructured to T3-min double-buffer (stage next while
//   computing cur, 1 barrier/K-step) + T2 XOR swizzle on A/B tiles
//   (inverse-swizzled global source, swizzled ds_read) — same pattern that
//   took attn from 92->~28us.
// ---------------------------------------------------------------------------

typedef unsigned short bh16;                                  // bf16 bits
typedef __bf16 bf16x8 __attribute__((ext_vector_type(8)));
typedef float f32x4 __attribute__((ext_vector_type(4)));
typedef unsigned int u32x4 __attribute__((ext_vector_type(4)));
typedef unsigned int u32x2 __attribute__((ext_vector_type(2)));

#define DEVI static __device__ __forceinline__

DEVI bh16 f2bf(float f) {
  union { float f; unsigned u; } x; x.f = f;
  unsigned r = x.u + 0x7fffu + ((x.u >> 16) & 1u);
  return (bh16)(r >> 16);
}
DEVI float bf2f(bh16 u) {
  union { unsigned u; float f; } x; x.u = ((unsigned)u) << 16; return x.f;
}
DEVI bf16x8 ld16(const bh16* p) {
  return __builtin_bit_cast(bf16x8, *(const u32x4*)p);
}
DEVI bf16x8 ld16b(const char* p) {
  return __builtin_bit_cast(bf16x8, *(const u32x4*)p);
}
DEVI f32x4 mfma16(bf16x8 a, bf16x8 b, f32x4 c) {
  return __builtin_amdgcn_mfma_f32_16x16x32_bf16(a, b, c, 0, 0, 0);
}
DEVI void async16(const void* g, void* l) {
  __builtin_amdgcn_global_load_lds(
      (const __attribute__((address_space(1))) void*)g,
      (__attribute__((address_space(3))) void*)l, 16, 0, 0);
}

// ---------------------------------------------------------------------------
// Weight transpose + f32->bf16 convert: in [K][N] f32 -> out [N][K] bf16.
// ---------------------------------------------------------------------------
__global__ __launch_bounds__(256) void tcvt(
    const float* __restrict__ in, bh16* __restrict__ out,
    int K, int N, long long inLS, long long outLS, int rowOff) {
  int l = blockIdx.z;
  in += (size_t)l * inLS;
  out += (size_t)l * outLS + (size_t)rowOff * K;
  __shared__ float t[32][33];
  int n0 = blockIdx.x * 32, k0 = blockIdx.y * 32;
  int tx = threadIdx.x & 31, ty = threadIdx.x >> 5;  // 32 x 8
#pragma unroll
  for (int i = 0; i < 4; i++)
    t[ty + 8 * i][tx] = in[(size_t)(k0 + ty + 8 * i) * N + n0 + tx];
  __syncthreads();
#pragma unroll
  for (int i = 0; i < 4; i++)
    out[(size_t)(n0 + ty + 8 * i) * K + k0 + tx] = f2bf(t[tx][ty + 8 * i]);
}

// bias concat: bq|bk|bv -> [L][1536] f32
__global__ __launch_bounds__(256) void bcat(
    const float* __restrict__ bq, const float* __restrict__ bk,
    const float* __restrict__ bv, float* __restrict__ out) {
  int l = blockIdx.x;
  for (int j = threadIdx.x; j < 1536; j += 256) {
    float v = (j < 512) ? bq[l * 512 + j]
            : (j < 1024) ? bk[l * 512 + j - 512] : bv[l * 512 + j - 1024];
    out[l * 1536 + j] = v;
  }
}

// f32 -> bf16 convert (padded_input)
__global__ __launch_bounds__(256) void cvt_in(
    const float* __restrict__ in, bh16* __restrict__ out, int n4) {
  int i = blockIdx.x * 256 + threadIdx.x;
  if (i < n4) {
    float4 v = ((const float4*)in)[i];
    u32x2 pk;
    pk[0] = (unsigned)f2bf(v.x) | ((unsigned)f2bf(v.y) << 16);
    pk[1] = (unsigned)f2bf(v.z) | ((unsigned)f2bf(v.w) << 16);
    *(u32x2*)(out + (size_t)i * 4) = pk;
  }
}

// ---------------------------------------------------------------------------
// GEMM: C[M][N] = A[M][K](bf16) * Bt[N][K](bf16)^T + bias.
// T3-min double-buffer: stage(kt+1) issued before compute(kt); one barrier
// per K-step (vmcnt drained there by compiler). T2 XOR swizzle: source byte
// col ^ ((row&7)<<4) with linear LDS dest; reads apply the same XOR.
// 1-D grid, XCD super-tile swizzle (8 m-panels per XCD -> A+B window in L2).
// QKV=1: n0>=1024 blocks write vt[(b*512+vc)][t] directly.
// ---------------------------------------------------------------------------
template <int BM, int BN, int RELU, int OUTF32, int QKV>
__global__ __launch_bounds__(256) void gemm_bt(
    const bh16* __restrict__ A, const bh16* __restrict__ Bt,
    const float* __restrict__ bias, void* __restrict__ Cout,
    bh16* __restrict__ vtOut, int M, int N, int K) {
  constexpr int BK = 64;
  __shared__ __align__(16) bh16 As[2][BM * BK];
  __shared__ __align__(16) bh16 Bs[2][BN * BK];
  const int tid = threadIdx.x;
  const int wave = tid >> 6, lane = tid & 63;
  const int lq = lane & 15, grp = lane >> 4;
  const int p = blockIdx.x;
  const int xcd = p & 7, idx = p >> 3;
  const int m0 = (((xcd << 3) | (idx & 7))) * BM;
  const int n0 = (idx >> 3) * BN;
  constexpr int FM = BM / 32, FN = BN / 32;
  const int wr = wave >> 1, wc = wave & 1;
  f32x4 acc[FM][FN] = {};

  const int nk = K / BK;
  auto stage = [&](int buf, int kt) {
#pragma unroll
    for (int i = 0; i < BM / 32; ++i) {
      int off = i * 4096 + wave * 1024 + lane * 16;
      int row = off >> 7, col = off & 127;
      int sw = (row & 7) << 4;
      const char* g =
          (const char*)A + ((size_t)(m0 + row) * K + kt * BK) * 2 + (col ^ sw);
      async16(g, (char*)As[buf] + off);
    }
#pragma unroll
    for (int i = 0; i < BN / 32; ++i) {
      int off = i * 4096 + wave * 1024 + lane * 16;
      int row = off >> 7, col = off & 127;
      int sw = (row & 7) << 4;
      const char* g =
          (const char*)Bt + ((size_t)(n0 + row) * K + kt * BK) * 2 + (col ^ sw);
      async16(g, (char*)Bs[buf] + off);
    }
  };

  stage(0, 0);
  for (int kt = 0; kt < nk; ++kt) {
    int cur = kt & 1;
    __syncthreads();                 // stage(kt) landed; prev readers done
    if (kt + 1 < nk) stage(cur ^ 1, kt + 1);
#pragma unroll
    for (int kk = 0; kk < 2; ++kk) {
      bf16x8 af[FM], bfr[FN];
#pragma unroll
      for (int i = 0; i < FM; ++i) {
        int row = wr * (BM / 2) + i * 16 + lq;
        int sw = (row & 7) << 4;
        af[i] = ld16b((char*)As[cur] + row * 128 + ((kk * 64 + grp * 16) ^ sw));
      }
#pragma unroll
      for (int j = 0; j < FN; ++j) {
        int row = wc * (BN / 2) + j * 16 + lq;
        int sw = (row & 7) << 4;
        bfr[j] = ld16b((char*)Bs[cur] + row * 128 + ((kk * 64 + grp * 16) ^ sw));
      }
#pragma unroll
      for (int i = 0; i < FM; ++i)
#pragma unroll
        for (int j = 0; j < FN; ++j)
          acc[i][j] = mfma16(af[i], bfr[j], acc[i][j]);
    }
  }
  // epilogue: D layout col=lane&15, row=(lane>>4)*4+r  [m89-verified]
  if (QKV && n0 >= 1024) {
#pragma unroll
    for (int i = 0; i < FM; ++i) {
#pragma unroll
      for (int j = 0; j < FN; ++j) {
        int col = n0 + wc * (BN / 2) + j * 16 + lq;
        float bv = bias[col];
        int vc = col - 1024;
        int t0 = m0 + wr * (BM / 2) + i * 16 + grp * 4;
        int bb = t0 >> 10, tl = t0 & 1023;
        u32x2 pk;
        pk[0] = (unsigned)f2bf(acc[i][j][0] + bv) |
                ((unsigned)f2bf(acc[i][j][1] + bv) << 16);
        pk[1] = (unsigned)f2bf(acc[i][j][2] + bv) |
                ((unsigned)f2bf(acc[i][j][3] + bv) << 16);
        *(u32x2*)&vtOut[((size_t)(bb * 512 + vc)) * 1024 + tl] = pk;
      }
    }
    return;
  }
#pragma unroll
  for (int i = 0; i < FM; ++i) {
#pragma unroll
    for (int j = 0; j < FN; ++j) {
      int col = n0 + wc * (BN / 2) + j * 16 + lq;
      float bv = bias[col];
#pragma unroll
      for (int r = 0; r < 4; ++r) {
        int row = m0 + wr * (BM / 2) + i * 16 + grp * 4 + r;
        float v = acc[i][j][r] + bv;
        if (RELU) v = fmaxf(v, 0.f);
        if (OUTF32) ((float*)Cout)[(size_t)row * N + col] = v;
        else ((bh16*)Cout)[(size_t)row * N + col] = f2bf(v);
      }
    }
  }
}

// ---------------------------------------------------------------------------
// LayerNorm after input projection: xb/xf = LN(in)*g+b + pe[t]  (f32 in)
// ---------------------------------------------------------------------------
__global__ __launch_bounds__(256) void ln_pe_k(
    const float* __restrict__ in, const float* __restrict__ g,
    const float* __restrict__ bta, const float* __restrict__ pe,
    float* __restrict__ xf, bh16* __restrict__ xb) {
  int wave = threadIdx.x >> 6, lane = threadIdx.x & 63;
  int row = blockIdx.x * 4 + wave;
  int t = row & 1023;
  const float* xr = in + (size_t)row * 512 + lane * 8;
  float4 a0 = ((const float4*)xr)[0], a1 = ((const float4*)xr)[1];
  float v[8] = {a0.x, a0.y, a0.z, a0.w, a1.x, a1.y, a1.z, a1.w};
  float s = 0.f, ss = 0.f;
#pragma unroll
  for (int j = 0; j < 8; j++) { s += v[j]; ss += v[j] * v[j]; }
#pragma unroll
  for (int m = 1; m < 64; m <<= 1) { s += __shfl_xor(s, m); ss += __shfl_xor(ss, m); }
  float mu = s * (1.f / 512.f);
  float rstd = rsqrtf(ss * (1.f / 512.f) - mu * mu + 1e-5f);
  int c0 = lane * 8;
  float o[8];
  u32x4 pk;
#pragma unroll
  for (int j = 0; j < 8; j++) {
    int c = c0 + j;
    o[j] = (v[j] - mu) * rstd * g[c] + bta[c] + pe[(size_t)t * 512 + c];
  }
  float4* xo = (float4*)(xf + (size_t)row * 512 + c0);
  xo[0] = make_float4(o[0], o[1], o[2], o[3]);
  xo[1] = make_float4(o[4], o[5], o[6], o[7]);
#pragma unroll
  for (int j = 0; j < 4; j++)
    pk[j] = (unsigned)f2bf(o[2 * j]) | ((unsigned)f2bf(o[2 * j + 1]) << 16);
  *(u32x4*)(xb + (size_t)row * 512 + c0) = pk;
}

// ---------------------------------------------------------------------------
// LayerNorm with residual + pad-mask: out = LN(gout(bf16) + res)*g+b * nonpad
// ---------------------------------------------------------------------------
__global__ __launch_bounds__(256) void ln_res_k(
    const bh16* __restrict__ gout, const float* __restrict__ res,
    const float* __restrict__ g, const float* __restrict__ bta,
    const int* __restrict__ lens,
    float* __restrict__ xf, bh16* __restrict__ xb) {
  int wave = threadIdx.x >> 6, lane = threadIdx.x & 63;
  int row = blockIdx.x * 4 + wave;
  int b = row >> 10, t = row & 1023;
  float nonpad = (t < lens[b]) ? 1.f : 0.f;
  int c0 = lane * 8;
  u32x4 graw = *(const u32x4*)(gout + (size_t)row * 512 + c0);
  const float* rr = res + (size_t)row * 512 + c0;
  float4 r0 = ((const float4*)rr)[0], r1 = ((const float4*)rr)[1];
  float v[8];
#pragma unroll
  for (int j = 0; j < 4; j++) {
    v[2 * j] = bf2f((bh16)(graw[j] & 0xffffu));
    v[2 * j + 1] = bf2f((bh16)(graw[j] >> 16));
  }
  v[0] += r0.x; v[1] += r0.y; v[2] += r0.z; v[3] += r0.w;
  v[4] += r1.x; v[5] += r1.y; v[6] += r1.z; v[7] += r1.w;
  float s = 0.f, ss = 0.f;
#pragma unroll
  for (int j = 0; j < 8; j++) { s += v[j]; ss += v[j] * v[j]; }
#pragma unroll
  for (int m = 1; m < 64; m <<= 1) { s += __shfl_xor(s, m); ss += __shfl_xor(ss, m); }
  float mu = s * (1.f / 512.f);
  float rstd = rsqrtf(ss * (1.f / 512.f) - mu * mu + 1e-5f);
  float o[8];
  u32x4 pk;
#pragma unroll
  for (int j = 0; j < 8; j++) {
    int c = c0 + j;
    o[j] = ((v[j] - mu) * rstd * g[c] + bta[c]) * nonpad;
  }
  float4* xo = (float4*)(xf + (size_t)row * 512 + c0);
  xo[0] = make_float4(o[0], o[1], o[2], o[3]);
  xo[1] = make_float4(o[4], o[5], o[6], o[7]);
#pragma unroll
  for (int j = 0; j < 4; j++)
    pk[j] = (unsigned)f2bf(o[2 * j]) | ((unsigned)f2bf(o[2 * j + 1]) << 16);
  *(u32x4*)(xb + (size_t)row * 512 + c0) = pk;
}

// ---------------------------------------------------------------------------
// Fused flash attention, staged 2-phase, 8 waves x 16 q = 128 q-rows/block.
// grid 512 = {8 qt x 64 bh}, XCD-swizzled (same bh -> same XCD). Per 64-key
// iter: sync -> stage(next K[64][64]+Vt[64][64], T2 swizzle) -> compute.
// ---------------------------------------------------------------------------
__global__ __launch_bounds__(512) void attn_k(
    const bh16* __restrict__ qkv, const bh16* __restrict__ vt,
    const int* __restrict__ lens, bh16* __restrict__ o) {
  constexpr int LDP = 72;
  __shared__ __align__(16) char Ks[2][8192];   // [key 0..63][d 0..63] swz
  __shared__ __align__(16) char Vs[2][8192];   // [d 0..63][t 0..63] swz
  __shared__ __align__(16) bh16 P[8][16 * LDP];
  int p = blockIdx.x;
  int xcd = p & 7, s = p >> 3;          // s in 0..63
  int bh = ((s & 7) << 3) | xcd;
  int qt = s >> 3;                      // 0..7
  int b = bh >> 3, h = bh & 7;
  int len = lens[b];
  if (qt * 128 >= len) return;
  int tid = threadIdx.x;
  int wave = tid >> 6, lane = tid & 63;
  int lq = lane & 15, grp = lane >> 4;

  size_t qrow = (size_t)(b * 1024 + qt * 128 + wave * 16 + lq);
  const bh16* Qp = qkv + qrow * 1536 + h * 64;
  bf16x8 qf0 = ld16(Qp + grp * 8);
  bf16x8 qf1 = ld16(Qp + 32 + grp * 8);
  const char* Kbase = (const char*)(qkv + (size_t)(b * 1024) * 1536 + 512 + h * 64);
  const char* Vbase = (const char*)(vt + (size_t)(bh * 64) * 1024);
  bh16* Pw = P[wave];

  f32x4 oacc[4] = {};
  float m = -1e30f, lsum = 0.f;
  int nkb = (len + 63) >> 6;

  auto stage = [&](int buf, int kb) {
    int off = tid * 16;
    int row = off >> 7, cb = off & 127;
    int sw = (row & 7) << 4;
    async16(Kbase + (size_t)(kb * 64 + row) * 3072 + (cb ^ sw), Ks[buf] + off);
    async16(Vbase + (size_t)row * 2048 + kb * 128 + (cb ^ sw), Vs[buf] + off);
  };

  stage(0, 0);
  for (int kb = 0; kb < nkb; ++kb) {
    int cur = kb & 1;
    __syncthreads();
    if (kb + 1 < nkb) stage(cur ^ 1, kb + 1);
    int k64 = kb * 64;
    f32x4 st[4];
    __builtin_amdgcn_s_setprio(1);
#pragma unroll
    for (int sv = 0; sv < 4; ++sv) {
      int row = sv * 16 + lq, sw = (row & 7) << 4;
      const char* kp = Ks[cur] + row * 128;
      f32x4 z = {};
      z = mfma16(ld16b(kp + ((grp * 16) ^ sw)), qf0, z);
      z = mfma16(ld16b(kp + ((64 + grp * 16) ^ sw)), qf1, z);
      st[sv] = z;
    }
    __builtin_amdgcn_s_setprio(0);
    float tmax = -1e30f;
    if (k64 + 64 > len) {
#pragma unroll
      for (int sv = 0; sv < 4; ++sv)
#pragma unroll
        for (int r = 0; r < 4; ++r) {
          int key = k64 + sv * 16 + grp * 4 + r;
          float v = st[sv][r] * 0.125f;
          v = (key < len) ? v : -1e30f;
          st[sv][r] = v;
          tmax = fmaxf(tmax, v);
        }
    } else {
#pragma unroll
      for (int sv = 0; sv < 4; ++sv)
#pragma unroll
        for (int r = 0; r < 4; ++r) {
          float v = st[sv][r] * 0.125f;
          st[sv][r] = v;
          tmax = fmaxf(tmax, v);
        }
    }
    tmax = fmaxf(tmax, __shfl_xor(tmax, 16));
    tmax = fmaxf(tmax, __shfl_xor(tmax, 32));
    float newm = fmaxf(m, tmax);
    if (!__all(newm - m <= 8.f)) {
      float sc = __expf(m - newm);
      m = newm;
      lsum *= sc;
#pragma unroll
      for (int r = 0; r < 4; ++r) {
        float scr = __shfl(sc, grp * 4 + r);
#pragma unroll
        for (int dt = 0; dt < 4; ++dt) oacc[dt][r] *= scr;
      }
    }
    float rs = 0.f;
#pragma unroll
    for (int sv = 0; sv < 4; ++sv) {
      float p0 = __expf(st[sv][0] - m), p1 = __expf(st[sv][1] - m);
      float p2 = __expf(st[sv][2] - m), p3 = __expf(st[sv][3] - m);
      rs += (p0 + p1) + (p2 + p3);
      u32x2 pk;
      pk[0] = (unsigned)f2bf(p0) | ((unsigned)f2bf(p1) << 16);
      pk[1] = (unsigned)f2bf(p2) | ((unsigned)f2bf(p3) << 16);
      *(u32x2*)&Pw[lq * LDP + sv * 16 + grp * 4] = pk;
    }
    rs += __shfl_xor(rs, 16);
    rs += __shfl_xor(rs, 32);
    lsum += rs;
#pragma unroll
    for (int kk = 0; kk < 2; ++kk) {
      bf16x8 pa = ld16(Pw + lq * LDP + kk * 32 + grp * 8);
      __builtin_amdgcn_s_setprio(1);
#pragma unroll
      for (int dt = 0; dt < 4; ++dt) {
        int row = dt * 16 + lq, sw = (row & 7) << 4;
        bf16x8 vfr = ld16b(Vs[cur] + row * 128 + ((kk * 64 + grp * 16) ^ sw));
        oacc[dt] = mfma16(pa, vfr, oacc[dt]);
      }
      __builtin_amdgcn_s_setprio(0);
    }
  }
#pragma unroll
  for (int r = 0; r < 4; ++r) {
    float li = __shfl(lsum, grp * 4 + r);
    float inv = 1.f / li;
    int row = qt * 128 + wave * 16 + grp * 4 + r;
    bh16* orow = o + (size_t)(b * 1024 + row) * 512 + h * 64;
#pragma unroll
    for (int dt = 0; dt < 4; ++dt) orow[dt * 16 + lq] = f2bf(oacc[dt][r] * inv);
  }
}

// ---------------------------------------------------------------------------
// host
// ---------------------------------------------------------------------------
extern "C" void kernel_launch(void* const* d_in, const int* in_sizes, int n_in,
                              void* d_out, int out_size, void* d_ws, size_t ws_size,
                              hipStream_t stream) {
  const float* padded = (const float*)d_in[0];
  const int* lens = (const int*)d_in[1];
  const float* w_in = (const float*)d_in[2];
  const float* b_in = (const float*)d_in[3];
  const float* ln_in_g = (const float*)d_in[4];
  const float* ln_in_b = (const float*)d_in[5];
  const float* pe = (const float*)d_in[6];
  const float* wq = (const float*)d_in[7];
  const float* bq = (const float*)d_in[8];
  const float* wk = (const float*)d_in[9];
  const float* bk = (const float*)d_in[10];
  const float* wv = (const float*)d_in[11];
  const float* bv = (const float*)d_in[12];
  const float* wfc = (const float*)d_in[13];
  const float* bfc = (const float*)d_in[14];
  const float* ln1_g = (const float*)d_in[15];
  const float* ln1_b = (const float*)d_in[16];
  const float* w1 = (const float*)d_in[17];
  const float* b1 = (const float*)d_in[18];
  const float* w2 = (const float*)d_in[19];
  const float* b2 = (const float*)d_in[20];
  const float* ln2_g = (const float*)d_in[21];
  const float* ln2_b = (const float*)d_in[22];

  char* ws = (char*)d_ws;
  size_t off = 0;
  auto alloc = [&](size_t bytes) -> char* {
    char* p = ws + off;
    off += (bytes + 255) & ~(size_t)255;
    return p;
  };
  bh16* WinT  = (bh16*)alloc((size_t)512 * 320 * 2);
  bh16* WqkvT = (bh16*)alloc((size_t)6 * 1536 * 512 * 2);
  bh16* WfcT  = (bh16*)alloc((size_t)6 * 512 * 512 * 2);
  bh16* W1T   = (bh16*)alloc((size_t)6 * 2048 * 512 * 2);
  bh16* W2T   = (bh16*)alloc((size_t)6 * 512 * 2048 * 2);
  float* bqkv = (float*)alloc((size_t)6 * 1536 * 4);
  bh16* xb    = (bh16*)alloc((size_t)8192 * 512 * 2);
  float* xf   = (float*)alloc((size_t)8192 * 512 * 4);
  bh16* qkvb  = (bh16*)alloc((size_t)8192 * 1536 * 2);
  bh16* vt    = (bh16*)alloc((size_t)64 * 64 * 1024 * 2);
  bh16* ob    = (bh16*)alloc((size_t)8192 * 512 * 2);
  float* tmp32 = (float*)alloc((size_t)8192 * 512 * 4);
  bh16* tmp16 = (bh16*)alloc((size_t)8192 * 512 * 2);
  bh16* hbuf  = (bh16*)alloc((size_t)8192 * 2048 * 2);
  bh16* padb  = hbuf;  // alias: hbuf is free until w1 GEMM
  if (off > ws_size) return;  // loud failure (output stays poisoned)

  // weights -> bf16 transposed
  tcvt<<<dim3(16, 10, 1), 256, 0, stream>>>(w_in, WinT, 320, 512, 0, 0, 0);
  tcvt<<<dim3(16, 16, 6), 256, 0, stream>>>(wq, WqkvT, 512, 512, 512 * 512, 1536 * 512, 0);
  tcvt<<<dim3(16, 16, 6), 256, 0, stream>>>(wk, WqkvT, 512, 512, 512 * 512, 1536 * 512, 512);
  tcvt<<<dim3(16, 16, 6), 256, 0, stream>>>(wv, WqkvT, 512, 512, 512 * 512, 1536 * 512, 1024);
  tcvt<<<dim3(16, 16, 6), 256, 0, stream>>>(wfc, WfcT, 512, 512, 512 * 512, 512 * 512, 0);
  tcvt<<<dim3(64, 16, 6), 256, 0, stream>>>(w1, W1T, 512, 2048, (long long)512 * 2048, (long long)2048 * 512, 0);
  tcvt<<<dim3(16, 64, 6), 256, 0, stream>>>(w2, W2T, 2048, 512, (long long)2048 * 512, (long long)512 * 2048, 0);
  bcat<<<6, 256, 0, stream>>>(bq, bk, bv, bqkv);
  cvt_in<<<2560, 256, 0, stream>>>(padded, padb, 655360);

  // input projection + LN + PE
  gemm_bt<128, 64, 0, 1, 0><<<512, 256, 0, stream>>>(
      padb, WinT, b_in, tmp32, nullptr, 8192, 512, 320);
  ln_pe_k<<<2048, 256, 0, stream>>>(tmp32, ln_in_g, ln_in_b, pe, xf, xb);

  for (int l = 0; l < 6; ++l) {
    gemm_bt<128, 128, 0, 0, 1><<<768, 256, 0, stream>>>(
        xb, WqkvT + (size_t)l * 1536 * 512, bqkv + l * 1536, qkvb, vt,
        8192, 1536, 512);
    attn_k<<<512, 512, 0, stream>>>(qkvb, vt, lens, ob);
    gemm_bt<128, 64, 0, 0, 0><<<512, 256, 0, stream>>>(
        ob, WfcT + (size_t)l * 512 * 512, bfc + l * 512, tmp16, nullptr,
        8192, 512, 512);
    ln_res_k<<<2048, 256, 0, stream>>>(tmp16, xf, ln1_g + l * 512, ln1_b + l * 512,
                                       lens, xf, xb);
    gemm_bt<128, 128, 1, 0, 0><<<1024, 256, 0, stream>>>(
        xb, W1T + (size_t)l * 2048 * 512, b1 + l * 2048, hbuf, nullptr,
        8192, 2048, 512);
    gemm_bt<128, 64, 0, 0, 0><<<512, 256, 0, stream>>>(
        hbuf, W2T + (size_t)l * 512 * 2048, b2 + l * 512, tmp16, nullptr,
        8192, 512, 2048);
    float* xfo = (l == 5) ? (float*)d_out : xf;
    ln_res_k<<<2048, 256, 0, stream>>>(tmp16, xf, ln2_g + l * 512, ln2_b + l * 512,
                                       lens, xfo, xb);
  }
}